// Round 2
// baseline (2754.693 us; speedup 1.0000x reference)
//
#include <hip/hip_runtime.h>

namespace {

constexpr int BATCH = 8;
constexpr int CH    = 256;   // C
constexpr int HW    = 2304;  // 48*48
constexpr int IMG   = 48;
constexpr int CG    = 64;    // fuse hidden channels

constexpr size_t SB     = (size_t)BATCH * CH * HW;   // floats per [B,C,HW] tensor
constexpr size_t HB_LEN = (size_t)BATCH * CG * HW;
constexpr size_t G0_LEN = (size_t)BATCH * HW;
constexpr size_t ROWS   = (size_t)BATCH * HW;
// ws layout (floats): Q K V | A1 A2 | HB | G0 | M | IS | E-chunk(nb batches)
constexpr size_t EC_OFF = 5 * SB + HB_LEN + G0_LEN + 2 * ROWS;  // 24,827,904 fl = 94.7 MiB

__device__ __forceinline__ void inner8x8(const float (&As)[16][132],
                                         const float (&Bs)[16][132],
                                         float (&acc)[8][8], int tx, int ty) {
#pragma unroll
    for (int kk = 0; kk < 16; ++kk) {
        float4 a0 = *reinterpret_cast<const float4*>(&As[kk][ty * 8]);
        float4 a1 = *reinterpret_cast<const float4*>(&As[kk][ty * 8 + 4]);
        float4 b0 = *reinterpret_cast<const float4*>(&Bs[kk][tx * 8]);
        float4 b1 = *reinterpret_cast<const float4*>(&Bs[kk][tx * 8 + 4]);
        float av[8]  = {a0.x, a0.y, a0.z, a0.w, a1.x, a1.y, a1.z, a1.w};
        float bvv[8] = {b0.x, b0.y, b0.z, b0.w, b1.x, b1.y, b1.z, b1.w};
#pragma unroll
        for (int i = 0; i < 8; ++i)
#pragma unroll
            for (int j = 0; j < 8; ++j)
                acc[i][j] = fmaf(av[i], bvv[j], acc[i][j]);
    }
}

// ---------------------------------------------------------------------------
// proj3: one attention's Q/K/V.  Y[b][m][n] = sum_k W[m][k]*X[b][k][n] (+bias)
// grid (18 n-tiles, 2 m-tiles, 3 projs * 8 batches), block 256
__global__ __launch_bounds__(256) void proj3_kernel(
    const float* __restrict__ Xq, const float* __restrict__ Xkv,
    const float* __restrict__ wq, const float* __restrict__ wk,
    const float* __restrict__ wv, const float* __restrict__ bv,
    float* __restrict__ Q, float* __restrict__ K, float* __restrict__ V)
{
    __shared__ float As[16][132];
    __shared__ float Bs[16][132];
    const int p = blockIdx.z >> 3;     // 0=Q 1=K 2=V
    const int b = blockIdx.z & 7;
    const float* X  = (p == 0) ? Xq : Xkv;
    const float* Wt = (p == 0) ? wq : (p == 1) ? wk : wv;
    const float* bias = (p == 2) ? bv : nullptr;
    float* Y = (p == 0) ? Q : (p == 1) ? K : V;

    const int t  = threadIdx.x;
    const int tx = t & 15, ty = t >> 4;
    const int m0 = blockIdx.y * 128;
    const int n0 = blockIdx.x * 128;
    const float* Xb = X + (size_t)b * CH * HW;

    float acc[8][8] = {};
    const int arow = t >> 1, ahalf = t & 1;
    const int bkk = t >> 4, bseg = t & 15;

    for (int k0 = 0; k0 < CH; k0 += 16) {
        float4 wa0 = *reinterpret_cast<const float4*>(&Wt[(size_t)(m0 + arow) * CH + k0 + ahalf * 8]);
        float4 wa1 = *reinterpret_cast<const float4*>(&Wt[(size_t)(m0 + arow) * CH + k0 + ahalf * 8 + 4]);
        float4 xb0 = *reinterpret_cast<const float4*>(&Xb[(size_t)(k0 + bkk) * HW + n0 + bseg * 8]);
        float4 xb1 = *reinterpret_cast<const float4*>(&Xb[(size_t)(k0 + bkk) * HW + n0 + bseg * 8 + 4]);
        const int ak = ahalf * 8;
        As[ak + 0][arow] = wa0.x; As[ak + 1][arow] = wa0.y;
        As[ak + 2][arow] = wa0.z; As[ak + 3][arow] = wa0.w;
        As[ak + 4][arow] = wa1.x; As[ak + 5][arow] = wa1.y;
        As[ak + 6][arow] = wa1.z; As[ak + 7][arow] = wa1.w;
        *reinterpret_cast<float4*>(&Bs[bkk][bseg * 8])     = xb0;
        *reinterpret_cast<float4*>(&Bs[bkk][bseg * 8 + 4]) = xb1;
        __syncthreads();
        inner8x8(As, Bs, acc, tx, ty);
        __syncthreads();
    }
#pragma unroll
    for (int i = 0; i < 8; ++i) {
        const int m = m0 + ty * 8 + i;
        const float bb = bias ? bias[m] : 0.f;
        float* dst = Y + ((size_t)b * CH + m) * HW + n0 + tx * 8;
        *reinterpret_cast<float4*>(dst) =
            make_float4(acc[i][0] + bb, acc[i][1] + bb, acc[i][2] + bb, acc[i][3] + bb);
        *reinterpret_cast<float4*>(dst + 4) =
            make_float4(acc[i][4] + bb, acc[i][5] + bb, acc[i][6] + bb, acc[i][7] + bb);
    }
}

// ---------------------------------------------------------------------------
// energy: E[z][i][j] = sum_k Q[b][k][i] * K[b][k][j], b = bofs + z
// grid (18 j-tiles, 18 i-tiles, nbc), block 256
__global__ __launch_bounds__(256) void energy_kernel(
    const float* __restrict__ Q, const float* __restrict__ Km,
    float* __restrict__ E, int bofs)
{
    __shared__ float As[16][132];
    __shared__ float Bs[16][132];
    const int b = bofs + blockIdx.z;
    const int t = threadIdx.x, tx = t & 15, ty = t >> 4;
    const int i0 = blockIdx.y * 128, j0 = blockIdx.x * 128;
    const float* Qb = Q  + (size_t)b * CH * HW;
    const float* Kb = Km + (size_t)b * CH * HW;
    float* Eb = E + (size_t)blockIdx.z * HW * HW;
    float acc[8][8] = {};
    const int kk = t >> 4, seg = t & 15;
    for (int k0 = 0; k0 < CH; k0 += 16) {
        float4 qa0 = *reinterpret_cast<const float4*>(&Qb[(size_t)(k0 + kk) * HW + i0 + seg * 8]);
        float4 qa1 = *reinterpret_cast<const float4*>(&Qb[(size_t)(k0 + kk) * HW + i0 + seg * 8 + 4]);
        float4 kb0 = *reinterpret_cast<const float4*>(&Kb[(size_t)(k0 + kk) * HW + j0 + seg * 8]);
        float4 kb1 = *reinterpret_cast<const float4*>(&Kb[(size_t)(k0 + kk) * HW + j0 + seg * 8 + 4]);
        *reinterpret_cast<float4*>(&As[kk][seg * 8])     = qa0;
        *reinterpret_cast<float4*>(&As[kk][seg * 8 + 4]) = qa1;
        *reinterpret_cast<float4*>(&Bs[kk][seg * 8])     = kb0;
        *reinterpret_cast<float4*>(&Bs[kk][seg * 8 + 4]) = kb1;
        __syncthreads();
        inner8x8(As, Bs, acc, tx, ty);
        __syncthreads();
    }
#pragma unroll
    for (int i = 0; i < 8; ++i) {
        float* dst = Eb + (size_t)(i0 + ty * 8 + i) * HW + j0 + tx * 8;
        *reinterpret_cast<float4*>(dst)     = make_float4(acc[i][0], acc[i][1], acc[i][2], acc[i][3]);
        *reinterpret_cast<float4*>(dst + 4) = make_float4(acc[i][4], acc[i][5], acc[i][6], acc[i][7]);
    }
}

// ---------------------------------------------------------------------------
// rowstat: per row of E-chunk, M = rowmax, IS = 1/sum(exp(row-M)).
// grid (nbc*HW) blocks of 256; row r (chunk-local) -> global row bofs*HW + r
__global__ __launch_bounds__(256) void rowstat_kernel(
    const float* __restrict__ E, float* __restrict__ M, float* __restrict__ IS,
    int bofs)
{
    const float* p = E + (size_t)blockIdx.x * HW;
    const int t = threadIdx.x;
    float v[9];
#pragma unroll
    for (int i = 0; i < 9; ++i) v[i] = p[t + 256 * i];
    float mx = v[0];
#pragma unroll
    for (int i = 1; i < 9; ++i) mx = fmaxf(mx, v[i]);
#pragma unroll
    for (int off = 32; off > 0; off >>= 1) mx = fmaxf(mx, __shfl_xor(mx, off));
    __shared__ float rmax[4], rsum[4];
    if ((t & 63) == 0) rmax[t >> 6] = mx;
    __syncthreads();
    mx = fmaxf(fmaxf(rmax[0], rmax[1]), fmaxf(rmax[2], rmax[3]));
    float s = 0.f;
#pragma unroll
    for (int i = 0; i < 9; ++i) s += __expf(v[i] - mx);
#pragma unroll
    for (int off = 32; off > 0; off >>= 1) s += __shfl_xor(s, off);
    if ((t & 63) == 0) rsum[t >> 6] = s;
    __syncthreads();
    if (t == 0) {
        s = rsum[0] + rsum[1] + rsum[2] + rsum[3];
        const size_t g = (size_t)bofs * HW + blockIdx.x;
        M[g]  = mx;
        IS[g] = 1.f / s;
    }
}

// ---------------------------------------------------------------------------
// pv2: out[b][c][n] = gamma * sum_m V[b][c][m] * softmax(E)[n][m] + src[b][c][n]
// P applied on the fly: P = exp(E - M[n]) * IS[n].
// grid (18 n-tiles, 2 c-tiles, nbc), block 256
__global__ __launch_bounds__(256) void pv2_kernel(
    const float* __restrict__ V, const float* __restrict__ E,
    const float* __restrict__ M, const float* __restrict__ IS,
    const float* __restrict__ src, const float* __restrict__ gamma,
    float* __restrict__ out, int bofs)
{
    __shared__ float As[16][132];
    __shared__ float Bs[16][132];
    const int b = bofs + blockIdx.z;
    const int t = threadIdx.x, tx = t & 15, ty = t >> 4;
    const int ct0 = blockIdx.y * 128, n0 = blockIdx.x * 128;
    const float* Vb = V + (size_t)b * CH * HW;
    const float* Eb = E + (size_t)blockIdx.z * HW * HW;
    float acc[8][8] = {};
    const int row = t >> 1, half = t & 1;
    const float mrow  = M [(size_t)b * HW + n0 + row];
    const float isrow = IS[(size_t)b * HW + n0 + row];
    for (int k0 = 0; k0 < HW; k0 += 16) {
        float4 va0 = *reinterpret_cast<const float4*>(&Vb[(size_t)(ct0 + row) * HW + k0 + half * 8]);
        float4 va1 = *reinterpret_cast<const float4*>(&Vb[(size_t)(ct0 + row) * HW + k0 + half * 8 + 4]);
        float4 e0  = *reinterpret_cast<const float4*>(&Eb[(size_t)(n0 + row) * HW + k0 + half * 8]);
        float4 e1  = *reinterpret_cast<const float4*>(&Eb[(size_t)(n0 + row) * HW + k0 + half * 8 + 4]);
        const int hk = half * 8;
        As[hk + 0][row] = va0.x; As[hk + 1][row] = va0.y;
        As[hk + 2][row] = va0.z; As[hk + 3][row] = va0.w;
        As[hk + 4][row] = va1.x; As[hk + 5][row] = va1.y;
        As[hk + 6][row] = va1.z; As[hk + 7][row] = va1.w;
        Bs[hk + 0][row] = __expf(e0.x - mrow) * isrow;
        Bs[hk + 1][row] = __expf(e0.y - mrow) * isrow;
        Bs[hk + 2][row] = __expf(e0.z - mrow) * isrow;
        Bs[hk + 3][row] = __expf(e0.w - mrow) * isrow;
        Bs[hk + 4][row] = __expf(e1.x - mrow) * isrow;
        Bs[hk + 5][row] = __expf(e1.y - mrow) * isrow;
        Bs[hk + 6][row] = __expf(e1.z - mrow) * isrow;
        Bs[hk + 7][row] = __expf(e1.w - mrow) * isrow;
        __syncthreads();
        inner8x8(As, Bs, acc, tx, ty);
        __syncthreads();
    }
    const float g = gamma[0];
#pragma unroll
    for (int i = 0; i < 8; ++i) {
        const int c = ct0 + ty * 8 + i;
        const float* sp = src + ((size_t)b * CH + c) * HW + n0 + tx * 8;
        float* dst      = out + ((size_t)b * CH + c) * HW + n0 + tx * 8;
        float4 s0 = *reinterpret_cast<const float4*>(sp);
        float4 s1 = *reinterpret_cast<const float4*>(sp + 4);
        *reinterpret_cast<float4*>(dst) = make_float4(
            g * acc[i][0] + s0.x, g * acc[i][1] + s0.y, g * acc[i][2] + s0.z, g * acc[i][3] + s0.w);
        *reinterpret_cast<float4*>(dst + 4) = make_float4(
            g * acc[i][4] + s1.x, g * acc[i][5] + s1.y, g * acc[i][6] + s1.z, g * acc[i][7] + s1.w);
    }
}

// ---------------------------------------------------------------------------
// conv1 (3x3, 512->64) as implicit GEMM over K = 512*9, with ReLU+bias.
// grid (18 n-tiles, 1, 8), block 256. Tile 64(M) x 128(N).
__global__ __launch_bounds__(256) void conv1_kernel(
    const float* __restrict__ att1, const float* __restrict__ att2,
    const float* __restrict__ fw1, const float* __restrict__ fb1,
    float* __restrict__ hbuf)
{
    __shared__ float As[16][68];
    __shared__ float Bs[16][132];
    const int b = blockIdx.z;
    const int t = threadIdx.x, tx = t & 15, ty = t >> 4;
    const int n0 = blockIdx.x * 128;
    float acc[4][8] = {};
    const int arow = t >> 2, aseg = t & 3;
    const int bkk = t >> 4, bseg = t & 15;
    const float* a1b = att1 + (size_t)b * CH * HW;
    const float* a2b = att2 + (size_t)b * CH * HW;

    for (int k0 = 0; k0 < 4608; k0 += 16) {
        float4 w4 = *reinterpret_cast<const float4*>(&fw1[(size_t)arow * 4608 + k0 + aseg * 4]);
        As[aseg * 4 + 0][arow] = w4.x;
        As[aseg * 4 + 1][arow] = w4.y;
        As[aseg * 4 + 2][arow] = w4.z;
        As[aseg * 4 + 3][arow] = w4.w;
        {
            const int k  = k0 + bkk;
            const int ci = k / 9;
            const int tap = k - ci * 9;
            const int dy = tap / 3 - 1;
            const int dx = tap - (tap / 3) * 3 - 1;
            const float* sp = (ci < CH) ? (a1b + (size_t)ci * HW) : (a2b + (size_t)(ci - CH) * HW);
#pragma unroll
            for (int j = 0; j < 8; ++j) {
                const int n = n0 + bseg * 8 + j;
                const int y = n / IMG;
                const int x = n - y * IMG;
                const int yy = y + dy, xx = x + dx;
                float v = 0.f;
                if (yy >= 0 && yy < IMG && xx >= 0 && xx < IMG) v = sp[yy * IMG + xx];
                Bs[bkk][bseg * 8 + j] = v;
            }
        }
        __syncthreads();
#pragma unroll
        for (int kk2 = 0; kk2 < 16; ++kk2) {
            float4 a4 = *reinterpret_cast<const float4*>(&As[kk2][ty * 4]);
            float4 b0 = *reinterpret_cast<const float4*>(&Bs[kk2][tx * 8]);
            float4 b1 = *reinterpret_cast<const float4*>(&Bs[kk2][tx * 8 + 4]);
            float av[4]  = {a4.x, a4.y, a4.z, a4.w};
            float bvv[8] = {b0.x, b0.y, b0.z, b0.w, b1.x, b1.y, b1.z, b1.w};
#pragma unroll
            for (int i = 0; i < 4; ++i)
#pragma unroll
                for (int j = 0; j < 8; ++j)
                    acc[i][j] = fmaf(av[i], bvv[j], acc[i][j]);
        }
        __syncthreads();
    }
#pragma unroll
    for (int i = 0; i < 4; ++i) {
        const int m = ty * 4 + i;
        const float bb = fb1[m];
        float* dst = hbuf + ((size_t)b * CG + m) * HW + n0 + tx * 8;
        *reinterpret_cast<float4*>(dst) = make_float4(
            fmaxf(acc[i][0] + bb, 0.f), fmaxf(acc[i][1] + bb, 0.f),
            fmaxf(acc[i][2] + bb, 0.f), fmaxf(acc[i][3] + bb, 0.f));
        *reinterpret_cast<float4*>(dst + 4) = make_float4(
            fmaxf(acc[i][4] + bb, 0.f), fmaxf(acc[i][5] + bb, 0.f),
            fmaxf(acc[i][6] + bb, 0.f), fmaxf(acc[i][7] + bb, 0.f));
    }
}

// ---------------------------------------------------------------------------
// gates: per-pixel 3x3 conv (64->2) + 2-way softmax; store g0 only.
__global__ __launch_bounds__(256) void gates_kernel(
    const float* __restrict__ hbuf, const float* __restrict__ fw2,
    const float* __restrict__ fb2, float* __restrict__ g0buf)
{
    __shared__ float w2s[1152];
    const int t = threadIdx.x;
    for (int i = t; i < 1152; i += 256) w2s[i] = fw2[i];
    __syncthreads();
    const int idx = blockIdx.x * 256 + t;   // b*HW + n, exactly 72*256 = 18432
    const int b = idx / HW;
    const int n = idx - b * HW;
    const int y = n / IMG, x = n - (n / IMG) * IMG;
    float c0 = fb2[0], c1 = fb2[1];
    const float* hb = hbuf + (size_t)b * CG * HW;
    for (int ci = 0; ci < CG; ++ci) {
        const float* hp = hb + (size_t)ci * HW;
        const float* w0 = &w2s[ci * 9];
        const float* w1 = &w2s[576 + ci * 9];
#pragma unroll
        for (int tap = 0; tap < 9; ++tap) {
            const int dy = tap / 3 - 1, dx = tap % 3 - 1;
            const int yy = y + dy, xx = x + dx;
            if (yy >= 0 && yy < IMG && xx >= 0 && xx < IMG) {
                const float hv = hp[yy * IMG + xx];
                c0 = fmaf(hv, w0[tap], c0);
                c1 = fmaf(hv, w1[tap], c1);
            }
        }
    }
    g0buf[idx] = 1.f / (1.f + __expf(c1 - c0));
}

// ---------------------------------------------------------------------------
// blend: out = g0*att1 + (1-g0)*att2, float4-vectorized. grid 4608 exact.
__global__ __launch_bounds__(256) void blend_kernel(
    const float* __restrict__ att1, const float* __restrict__ att2,
    const float* __restrict__ g0buf, float* __restrict__ out)
{
    const int i = blockIdx.x * 256 + threadIdx.x;  // float4 index
    const int r = i / 576;                         // (b,c) row (HW/4 = 576)
    const int q = i - r * 576;
    const int b = r >> 8;
    const float4 a1 = reinterpret_cast<const float4*>(att1)[i];
    const float4 a2 = reinterpret_cast<const float4*>(att2)[i];
    const float4 g  = *reinterpret_cast<const float4*>(&g0buf[(size_t)b * HW + q * 4]);
    float4 o;
    o.x = g.x * a1.x + (1.f - g.x) * a2.x;
    o.y = g.y * a1.y + (1.f - g.y) * a2.y;
    o.z = g.z * a1.z + (1.f - g.z) * a2.z;
    o.w = g.w * a1.w + (1.f - g.w) * a2.w;
    reinterpret_cast<float4*>(out)[i] = o;
}

} // namespace

extern "C" void kernel_launch(void* const* d_in, const int* in_sizes, int n_in,
                              void* d_out, int out_size, void* d_ws, size_t ws_size,
                              hipStream_t stream)
{
    const float* x1  = (const float*)d_in[0];
    const float* x2  = (const float*)d_in[1];
    const float* wq1 = (const float*)d_in[2];
    const float* wk1 = (const float*)d_in[3];
    const float* wv1 = (const float*)d_in[4];
    const float* bv1 = (const float*)d_in[5];
    const float* g1  = (const float*)d_in[6];
    const float* wq2 = (const float*)d_in[7];
    const float* wk2 = (const float*)d_in[8];
    const float* wv2 = (const float*)d_in[9];
    const float* bv2 = (const float*)d_in[10];
    const float* g2  = (const float*)d_in[11];
    const float* fw1 = (const float*)d_in[12];
    const float* fb1 = (const float*)d_in[13];
    const float* fw2 = (const float*)d_in[14];
    const float* fb2 = (const float*)d_in[15];
    float* out = (float*)d_out;
    float* ws  = (float*)d_ws;

    float* Q  = ws + 0 * SB;
    float* K  = ws + 1 * SB;
    float* V  = ws + 2 * SB;
    float* A1 = ws + 3 * SB;
    float* A2 = ws + 4 * SB;
    float* HB = ws + 5 * SB;
    float* G0 = HB + HB_LEN;
    float* M  = G0 + G0_LEN;
    float* IS = M + ROWS;
    float* EC = ws + EC_OFF;   // nb * HW*HW fp32 energy chunk

    (void)in_sizes; (void)n_in; (void)out_size;

    // adaptive E-chunk batch count from the actual workspace size
    long nb = ((long)(ws_size / 4) - (long)EC_OFF) / ((long)HW * HW);
    if (nb < 1) nb = 1;
    if (nb > 8) nb = 8;

    for (int a = 0; a < 2; ++a) {
        const float* Xq  = (a == 0) ? x1 : x2;   // source
        const float* Xkv = (a == 0) ? x2 : x1;   // guidance
        const float* wq  = (a == 0) ? wq1 : wq2;
        const float* wk  = (a == 0) ? wk1 : wk2;
        const float* wv  = (a == 0) ? wv1 : wv2;
        const float* bv  = (a == 0) ? bv1 : bv2;
        const float* gm  = (a == 0) ? g1  : g2;
        float* A         = (a == 0) ? A1  : A2;

        proj3_kernel<<<dim3(18, 2, 24), 256, 0, stream>>>(
            Xq, Xkv, wq, wk, wv, bv, Q, K, V);

        for (int bofs = 0; bofs < BATCH; bofs += (int)nb) {
            const int nbc = ((int)nb < BATCH - bofs) ? (int)nb : (BATCH - bofs);
            energy_kernel<<<dim3(18, 18, nbc), 256, 0, stream>>>(Q, K, EC, bofs);
            rowstat_kernel<<<dim3(nbc * HW), 256, 0, stream>>>(EC, M, IS, bofs);
            pv2_kernel<<<dim3(18, 2, nbc), 256, 0, stream>>>(
                V, EC, M, IS, Xq, gm, A, bofs);
        }
    }

    conv1_kernel<<<dim3(18, 1, 8), 256, 0, stream>>>(A1, A2, fw1, fb1, HB);
    gates_kernel<<<dim3(72), 256, 0, stream>>>(HB, fw2, fb2, G0);
    blend_kernel<<<dim3(4608), 256, 0, stream>>>(A1, A2, G0, out);
}

// Round 3
// 754.442 us; speedup vs baseline: 3.6513x; 3.6513x over previous
//
#include <hip/hip_runtime.h>

namespace {

constexpr int BATCH = 8;
constexpr int CH    = 256;   // C
constexpr int HW    = 2304;  // 48*48
constexpr int IMG   = 48;
constexpr int CG    = 64;

typedef __bf16 bf16x8 __attribute__((ext_vector_type(8)));
typedef __bf16 bf16x4 __attribute__((ext_vector_type(4)));
typedef float  f32x4  __attribute__((ext_vector_type(4)));

constexpr int ROWB = 40;   // LDS row stride in bf16 elems (32 data + 8 pad = 80B)

// ---- ws layout (bytes) ----
constexpr size_t QT_OFF = 0;                                  // bf16 [B][HW][256]
constexpr size_t KT_OFF = QT_OFF + (size_t)BATCH*HW*CH*2;
constexpr size_t VB_OFF = KT_OFF + (size_t)BATCH*HW*CH*2;     // bf16 [B][256][HW]
constexpr size_t AT_OFF = VB_OFF + (size_t)BATCH*CH*HW*2;     // bf16 [B][HW][512]
constexpr size_t A1_OFF = AT_OFF + (size_t)BATCH*HW*512*2;    // f32 [B][256][HW]
constexpr size_t A2_OFF = A1_OFF + (size_t)BATCH*CH*HW*4;
constexpr size_t HB_OFF = A2_OFF + (size_t)BATCH*CH*HW*4;     // f32 [B][64][HW]
constexpr size_t MR_OFF = HB_OFF + (size_t)BATCH*CG*HW*4;     // f32 [B*HW]
constexpr size_t IS_OFF = MR_OFF + (size_t)BATCH*HW*4;
constexpr size_t G0_OFF = IS_OFF + (size_t)BATCH*HW*4;
constexpr size_t EC_OFF = G0_OFF + (size_t)BATCH*HW*4;        // f32 E chunk / conv partials
constexpr size_t EC_CHUNK = (size_t)HW*HW*4;                  // 21.2 MB per batch

// stage 16 bf16 elems/thread from row-major src (row stride in elems) into [128][ROWB] LDS
__device__ __forceinline__ void stage_bf16(const __bf16* __restrict__ src, size_t srcStride,
                                           __bf16* dst, int t) {
    const int r = t & 127, s = t >> 7;
    const bf16x8* sp = reinterpret_cast<const bf16x8*>(src + (size_t)r * srcStride + s * 16);
    bf16x8* dp = reinterpret_cast<bf16x8*>(dst + r * ROWB + s * 16);
    dp[0] = sp[0];
    dp[1] = sp[1];
}

// stage 16 fp32 elems/thread (convert to bf16) from row-major src into [128][ROWB] LDS
__device__ __forceinline__ void stage_f32(const float* __restrict__ src, size_t srcStride,
                                          __bf16* dst, int t) {
    const int r = t & 127, s = t >> 7;
    const float4* sp = reinterpret_cast<const float4*>(src + (size_t)r * srcStride + s * 16);
    float4 f0 = sp[0], f1 = sp[1], f2 = sp[2], f3 = sp[3];
    bf16x8 v0, v1;
    v0[0]=(__bf16)f0.x; v0[1]=(__bf16)f0.y; v0[2]=(__bf16)f0.z; v0[3]=(__bf16)f0.w;
    v0[4]=(__bf16)f1.x; v0[5]=(__bf16)f1.y; v0[6]=(__bf16)f1.z; v0[7]=(__bf16)f1.w;
    v1[0]=(__bf16)f2.x; v1[1]=(__bf16)f2.y; v1[2]=(__bf16)f2.z; v1[3]=(__bf16)f2.w;
    v1[4]=(__bf16)f3.x; v1[5]=(__bf16)f3.y; v1[6]=(__bf16)f3.z; v1[7]=(__bf16)f3.w;
    bf16x8* dp = reinterpret_cast<bf16x8*>(dst + r * ROWB + s * 16);
    dp[0] = v0;
    dp[1] = v1;
}

// 4-wave 128x128 MFMA step: each wave (wm,wn) owns 64x64; 16 mfma
__device__ __forceinline__ void frag_step(const __bf16* As, const __bf16* Bs,
                                          f32x4 (&acc)[4][4], int lane, int wm, int wn) {
    const int r = lane & 15, g = lane >> 4;
    bf16x8 a[4], b[4];
#pragma unroll
    for (int i = 0; i < 4; ++i) {
        a[i] = *reinterpret_cast<const bf16x8*>(As + (wm * 64 + i * 16 + r) * ROWB + g * 8);
        b[i] = *reinterpret_cast<const bf16x8*>(Bs + (wn * 64 + i * 16 + r) * ROWB + g * 8);
    }
#pragma unroll
    for (int i = 0; i < 4; ++i)
#pragma unroll
        for (int j = 0; j < 4; ++j)
            acc[i][j] = __builtin_amdgcn_mfma_f32_16x16x32_bf16(a[i], b[j], acc[i][j], 0, 0, 0);
}

// ---------------------------------------------------------------------------
// proj3: Q/K/V for one attention. Q,K stored TRANSPOSED bf16 [B][HW][256];
// V stored natural bf16 [B][256][HW] (+bias).
__global__ __launch_bounds__(256) void proj3_mfma(
    const float* __restrict__ Xsrc, const float* __restrict__ Xg,
    const float* __restrict__ wq, const float* __restrict__ wk,
    const float* __restrict__ wv, const float* __restrict__ bv,
    __bf16* __restrict__ QT, __bf16* __restrict__ KT, __bf16* __restrict__ VB)
{
    __shared__ __bf16 As[128 * ROWB];
    __shared__ __bf16 Bs[128 * ROWB];
    const int p = blockIdx.z >> 3;      // 0=Q 1=K 2=V
    const int b = blockIdx.z & 7;
    const float* W = (p == 0) ? wq : (p == 1) ? wk : wv;
    const float* X = (p == 0) ? Xsrc : Xg;
    const float* Xb = X + (size_t)b * CH * HW;

    const int t = threadIdx.x;
    const int lane = t & 63, wid = t >> 6;
    const int wm = wid >> 1, wn = wid & 1;
    const int m0 = blockIdx.y * 128, n0 = blockIdx.x * 128;

    f32x4 acc[4][4] = {};
    const int nB = t & 127, halfB = t >> 7;   // B-stage: thread owns col n, 16 k's

    for (int k0 = 0; k0 < CH; k0 += 32) {
        stage_f32(W + (size_t)m0 * CH + k0, CH, As, t);
        // B: transpose X[k][n] -> Bs[n][k]
        float v[16];
#pragma unroll
        for (int kk = 0; kk < 16; ++kk)
            v[kk] = Xb[(size_t)(k0 + halfB * 16 + kk) * HW + n0 + nB];
        bf16x8 p0, p1;
#pragma unroll
        for (int kk = 0; kk < 8; ++kk) { p0[kk] = (__bf16)v[kk]; p1[kk] = (__bf16)v[kk + 8]; }
        bf16x8* dp = reinterpret_cast<bf16x8*>(Bs + nB * ROWB + halfB * 16);
        dp[0] = p0; dp[1] = p1;
        __syncthreads();
        frag_step(As, Bs, acc, lane, wm, wn);
        __syncthreads();
    }

    const int g = lane >> 4, r = lane & 15;
    if (p < 2) {
        __bf16* T = (p == 0) ? QT : KT;
#pragma unroll
        for (int mi = 0; mi < 4; ++mi)
#pragma unroll
            for (int nj = 0; nj < 4; ++nj) {
                const int mb = m0 + wm * 64 + mi * 16 + g * 4;
                const int n  = n0 + wn * 64 + nj * 16 + r;
                bf16x4 pk;
#pragma unroll
                for (int q = 0; q < 4; ++q) pk[q] = (__bf16)acc[mi][nj][q];
                *reinterpret_cast<bf16x4*>(T + ((size_t)b * HW + n) * CH + mb) = pk;
            }
    } else {
#pragma unroll
        for (int mi = 0; mi < 4; ++mi)
#pragma unroll
            for (int nj = 0; nj < 4; ++nj) {
                const int mb = m0 + wm * 64 + mi * 16 + g * 4;
                const int n  = n0 + wn * 64 + nj * 16 + r;
#pragma unroll
                for (int q = 0; q < 4; ++q)
                    VB[((size_t)b * CH + mb + q) * HW + n] = (__bf16)(acc[mi][nj][q] + bv[mb + q]);
            }
    }
}

// ---------------------------------------------------------------------------
// energy: E[z][i][j] = sum_k QT[b][i][k] * KT[b][j][k]  (fp32 out)
__global__ __launch_bounds__(256) void energy_mfma(
    const __bf16* __restrict__ QT, const __bf16* __restrict__ KT,
    float* __restrict__ E, int bofs)
{
    __shared__ __bf16 As[128 * ROWB];
    __shared__ __bf16 Bs[128 * ROWB];
    const int b = bofs + blockIdx.z;
    const int t = threadIdx.x;
    const int lane = t & 63, wid = t >> 6;
    const int wm = wid >> 1, wn = wid & 1;
    const int i0 = blockIdx.y * 128, j0 = blockIdx.x * 128;
    const __bf16* Qb = QT + ((size_t)b * HW + i0) * CH;
    const __bf16* Kb = KT + ((size_t)b * HW + j0) * CH;
    float* Eb = E + (size_t)blockIdx.z * HW * HW;

    f32x4 acc[4][4] = {};
    for (int k0 = 0; k0 < CH; k0 += 32) {
        stage_bf16(Qb + k0, CH, As, t);
        stage_bf16(Kb + k0, CH, Bs, t);
        __syncthreads();
        frag_step(As, Bs, acc, lane, wm, wn);
        __syncthreads();
    }
    const int g = lane >> 4, r = lane & 15;
#pragma unroll
    for (int mi = 0; mi < 4; ++mi)
#pragma unroll
        for (int nj = 0; nj < 4; ++nj) {
            const int i = i0 + wm * 64 + mi * 16 + g * 4;
            const int j = j0 + wn * 64 + nj * 16 + r;
#pragma unroll
            for (int q = 0; q < 4; ++q)
                Eb[(size_t)(i + q) * HW + j] = acc[mi][nj][q];
        }
}

// ---------------------------------------------------------------------------
__global__ __launch_bounds__(256) void rowstat_kernel(
    const float* __restrict__ E, float* __restrict__ M, float* __restrict__ IS,
    int bofs)
{
    const float* p = E + (size_t)blockIdx.x * HW;
    const int t = threadIdx.x;
    float v[9];
#pragma unroll
    for (int i = 0; i < 9; ++i) v[i] = p[t + 256 * i];
    float mx = v[0];
#pragma unroll
    for (int i = 1; i < 9; ++i) mx = fmaxf(mx, v[i]);
#pragma unroll
    for (int off = 32; off > 0; off >>= 1) mx = fmaxf(mx, __shfl_xor(mx, off));
    __shared__ float rmax[4], rsum[4];
    if ((t & 63) == 0) rmax[t >> 6] = mx;
    __syncthreads();
    mx = fmaxf(fmaxf(rmax[0], rmax[1]), fmaxf(rmax[2], rmax[3]));
    float s = 0.f;
#pragma unroll
    for (int i = 0; i < 9; ++i) s += __expf(v[i] - mx);
#pragma unroll
    for (int off = 32; off > 0; off >>= 1) s += __shfl_xor(s, off);
    if ((t & 63) == 0) rsum[t >> 6] = s;
    __syncthreads();
    if (t == 0) {
        s = rsum[0] + rsum[1] + rsum[2] + rsum[3];
        const size_t gidx = (size_t)bofs * HW + blockIdx.x;
        M[gidx]  = mx;
        IS[gidx] = 1.f / s;
    }
}

// ---------------------------------------------------------------------------
// pv2: att[c][n] = gamma * sum_m VB[c][m] * P[n][m] + src[c][n]; P on the fly.
// Dual epilogue: A fp32 (blend path) + AT bf16 transposed slice (conv path).
__global__ __launch_bounds__(256) void pv2_mfma(
    const __bf16* __restrict__ VB, const float* __restrict__ E,
    const float* __restrict__ M, const float* __restrict__ IS,
    const float* __restrict__ src, const float* __restrict__ gamma,
    float* __restrict__ A, __bf16* __restrict__ AT, int aoff, int bofs)
{
    __shared__ __bf16 As[128 * ROWB];
    __shared__ __bf16 Bs[128 * ROWB];
    const int b = bofs + blockIdx.z;
    const int t = threadIdx.x;
    const int lane = t & 63, wid = t >> 6;
    const int wm = wid >> 1, wn = wid & 1;
    const int c0 = blockIdx.y * 128, n0 = blockIdx.x * 128;
    const __bf16* Vb = VB + ((size_t)b * CH + c0) * HW;
    const float* Eb  = E + (size_t)blockIdx.z * HW * HW;

    const int nB = t & 127, halfB = t >> 7;
    const float mrow  = M [(size_t)b * HW + n0 + nB];
    const float isrow = IS[(size_t)b * HW + n0 + nB];
    const float* Erow = Eb + (size_t)(n0 + nB) * HW;

    f32x4 acc[4][4] = {};
    for (int k0 = 0; k0 < HW; k0 += 32) {
        stage_bf16(Vb + k0, HW, As, t);
        const float4* ep = reinterpret_cast<const float4*>(Erow + k0 + halfB * 16);
        float4 e0 = ep[0], e1 = ep[1], e2 = ep[2], e3 = ep[3];
        bf16x8 p0, p1;
        p0[0]=(__bf16)(__expf(e0.x-mrow)*isrow); p0[1]=(__bf16)(__expf(e0.y-mrow)*isrow);
        p0[2]=(__bf16)(__expf(e0.z-mrow)*isrow); p0[3]=(__bf16)(__expf(e0.w-mrow)*isrow);
        p0[4]=(__bf16)(__expf(e1.x-mrow)*isrow); p0[5]=(__bf16)(__expf(e1.y-mrow)*isrow);
        p0[6]=(__bf16)(__expf(e1.z-mrow)*isrow); p0[7]=(__bf16)(__expf(e1.w-mrow)*isrow);
        p1[0]=(__bf16)(__expf(e2.x-mrow)*isrow); p1[1]=(__bf16)(__expf(e2.y-mrow)*isrow);
        p1[2]=(__bf16)(__expf(e2.z-mrow)*isrow); p1[3]=(__bf16)(__expf(e2.w-mrow)*isrow);
        p1[4]=(__bf16)(__expf(e3.x-mrow)*isrow); p1[5]=(__bf16)(__expf(e3.y-mrow)*isrow);
        p1[6]=(__bf16)(__expf(e3.z-mrow)*isrow); p1[7]=(__bf16)(__expf(e3.w-mrow)*isrow);
        bf16x8* dp = reinterpret_cast<bf16x8*>(Bs + nB * ROWB + halfB * 16);
        dp[0] = p0; dp[1] = p1;
        __syncthreads();
        frag_step(As, Bs, acc, lane, wm, wn);
        __syncthreads();
    }

    const float gm = gamma[0];
    const int g = lane >> 4, r = lane & 15;
#pragma unroll
    for (int mi = 0; mi < 4; ++mi)
#pragma unroll
        for (int nj = 0; nj < 4; ++nj) {
            const int cb = c0 + wm * 64 + mi * 16 + g * 4;
            const int n  = n0 + wn * 64 + nj * 16 + r;
            float vals[4];
#pragma unroll
            for (int q = 0; q < 4; ++q) {
                const size_t idx = ((size_t)b * CH + cb + q) * HW + n;
                vals[q] = gm * acc[mi][nj][q] + src[idx];
                A[idx] = vals[q];
            }
            bf16x4 pk;
#pragma unroll
            for (int q = 0; q < 4; ++q) pk[q] = (__bf16)vals[q];
            *reinterpret_cast<bf16x4*>(AT + ((size_t)b * HW + n) * 512 + aoff + cb) = pk;
        }
}

// ---------------------------------------------------------------------------
// conv1: 3x3 conv (512->64) via 9-tap shifted im2col MFMA GEMM, K split 4-way.
// grid (18 n-tiles, 4 k-chunks, 8 b); partials P4[kc][b][64][HW] fp32.
__global__ __launch_bounds__(256) void conv1_mfma(
    const __bf16* __restrict__ AT, const float* __restrict__ fw1,
    float* __restrict__ P4)
{
    __shared__ __bf16 As[64 * ROWB];
    __shared__ __bf16 Bs[128 * ROWB];
    const int kc = blockIdx.y;
    const int b  = blockIdx.z;
    const int n0 = blockIdx.x * 128;
    const int t = threadIdx.x;
    const int lane = t & 63, wid = t >> 6;          // wave owns n-offset wid*32

    const int rB = t & 127, sB = t >> 7;
    const int ng = n0 + rB;
    const int yy = ng / IMG, xx = ng - yy * IMG;
    const int mA = t >> 2, cqA = t & 3;

    f32x4 acc[4][2] = {};

    for (int tap = 0; tap < 9; ++tap) {
        const int dy = tap / 3 - 1, dx = tap % 3 - 1;
        const bool valid = ((unsigned)(yy + dy) < IMG) && ((unsigned)(xx + dx) < IMG);
        const int nn = ng + dy * IMG + dx;
#pragma unroll 1
        for (int st = 0; st < 4; ++st) {
            const int cbase = kc * 128 + st * 32;
            // A: fw1[m][ci*9+tap], 8 strided fp32 loads per thread
            {
                const float* wp = fw1 + (size_t)mA * 4608 + (size_t)(cbase + cqA * 8) * 9 + tap;
                bf16x8 pk;
#pragma unroll
                for (int i = 0; i < 8; ++i) pk[i] = (__bf16)wp[i * 9];
                *reinterpret_cast<bf16x8*>(As + mA * ROWB + cqA * 8) = pk;
            }
            // B: shifted att row (zero if out of image)
            {
                bf16x8 v0 = {}, v1 = {};
                if (valid) {
                    const bf16x8* sp = reinterpret_cast<const bf16x8*>(
                        AT + ((size_t)b * HW + nn) * 512 + cbase + sB * 16);
                    v0 = sp[0]; v1 = sp[1];
                }
                bf16x8* dp = reinterpret_cast<bf16x8*>(Bs + rB * ROWB + sB * 16);
                dp[0] = v0; dp[1] = v1;
            }
            __syncthreads();
            {
                const int r = lane & 15, g = lane >> 4;
                bf16x8 a[4], bb[2];
#pragma unroll
                for (int i = 0; i < 4; ++i)
                    a[i] = *reinterpret_cast<const bf16x8*>(As + (i * 16 + r) * ROWB + g * 8);
#pragma unroll
                for (int j = 0; j < 2; ++j)
                    bb[j] = *reinterpret_cast<const bf16x8*>(Bs + (wid * 32 + j * 16 + r) * ROWB + g * 8);
#pragma unroll
                for (int i = 0; i < 4; ++i)
#pragma unroll
                    for (int j = 0; j < 2; ++j)
                        acc[i][j] = __builtin_amdgcn_mfma_f32_16x16x32_bf16(a[i], bb[j], acc[i][j], 0, 0, 0);
            }
            __syncthreads();
        }
    }
    const int g = lane >> 4, r = lane & 15;
#pragma unroll
    for (int mi = 0; mi < 4; ++mi)
#pragma unroll
        for (int nj = 0; nj < 2; ++nj) {
            const int m = mi * 16 + g * 4;
            const int n = n0 + wid * 32 + nj * 16 + r;
#pragma unroll
            for (int q = 0; q < 4; ++q)
                P4[(((size_t)kc * BATCH + b) * CG + m + q) * HW + n] = acc[mi][nj][q];
        }
}

// ---------------------------------------------------------------------------
__global__ __launch_bounds__(256) void reduce_hb(
    const float* __restrict__ P4, const float* __restrict__ fb1,
    float* __restrict__ HB)
{
    const int idx = blockIdx.x * 256 + threadIdx.x;     // 8*64*2304 exactly
    constexpr size_t STRIDE = (size_t)BATCH * CG * HW;
    const int m = (idx / HW) & 63;
    float s = P4[idx] + P4[idx + STRIDE] + P4[idx + 2 * STRIDE] + P4[idx + 3 * STRIDE];
    HB[idx] = fmaxf(s + fb1[m], 0.f);
}

// ---------------------------------------------------------------------------
__global__ __launch_bounds__(256) void gates_kernel(
    const float* __restrict__ hbuf, const float* __restrict__ fw2,
    const float* __restrict__ fb2, float* __restrict__ g0buf)
{
    __shared__ float w2s[1152];
    const int t = threadIdx.x;
    for (int i = t; i < 1152; i += 256) w2s[i] = fw2[i];
    __syncthreads();
    const int idx = blockIdx.x * 256 + t;
    const int b = idx / HW;
    const int n = idx - b * HW;
    const int y = n / IMG, x = n - (n / IMG) * IMG;
    float c0 = fb2[0], c1 = fb2[1];
    const float* hb = hbuf + (size_t)b * CG * HW;
    for (int ci = 0; ci < CG; ++ci) {
        const float* hp = hb + (size_t)ci * HW;
        const float* w0 = &w2s[ci * 9];
        const float* w1 = &w2s[576 + ci * 9];
#pragma unroll
        for (int tap = 0; tap < 9; ++tap) {
            const int dy = tap / 3 - 1, dx = tap % 3 - 1;
            const int yy = y + dy, xxp = x + dx;
            if (yy >= 0 && yy < IMG && xxp >= 0 && xxp < IMG) {
                const float hv = hp[yy * IMG + xxp];
                c0 = fmaf(hv, w0[tap], c0);
                c1 = fmaf(hv, w1[tap], c1);
            }
        }
    }
    g0buf[idx] = 1.f / (1.f + __expf(c1 - c0));
}

// ---------------------------------------------------------------------------
__global__ __launch_bounds__(256) void blend_kernel(
    const float* __restrict__ att1, const float* __restrict__ att2,
    const float* __restrict__ g0buf, float* __restrict__ out)
{
    const int i = blockIdx.x * 256 + threadIdx.x;
    const int r = i / 576;
    const int q = i - r * 576;
    const int b = r >> 8;
    const float4 a1 = reinterpret_cast<const float4*>(att1)[i];
    const float4 a2 = reinterpret_cast<const float4*>(att2)[i];
    const float4 g  = *reinterpret_cast<const float4*>(&g0buf[(size_t)b * HW + q * 4]);
    float4 o;
    o.x = g.x * a1.x + (1.f - g.x) * a2.x;
    o.y = g.y * a1.y + (1.f - g.y) * a2.y;
    o.z = g.z * a1.z + (1.f - g.z) * a2.z;
    o.w = g.w * a1.w + (1.f - g.w) * a2.w;
    reinterpret_cast<float4*>(out)[i] = o;
}

} // namespace

extern "C" void kernel_launch(void* const* d_in, const int* in_sizes, int n_in,
                              void* d_out, int out_size, void* d_ws, size_t ws_size,
                              hipStream_t stream)
{
    const float* x1  = (const float*)d_in[0];
    const float* x2  = (const float*)d_in[1];
    const float* wq1 = (const float*)d_in[2];
    const float* wk1 = (const float*)d_in[3];
    const float* wv1 = (const float*)d_in[4];
    const float* bv1 = (const float*)d_in[5];
    const float* g1  = (const float*)d_in[6];
    const float* wq2 = (const float*)d_in[7];
    const float* wk2 = (const float*)d_in[8];
    const float* wv2 = (const float*)d_in[9];
    const float* bv2 = (const float*)d_in[10];
    const float* g2  = (const float*)d_in[11];
    const float* fw1 = (const float*)d_in[12];
    const float* fb1 = (const float*)d_in[13];
    const float* fw2 = (const float*)d_in[14];
    const float* fb2 = (const float*)d_in[15];
    float* out = (float*)d_out;
    char*  wsb = (char*)d_ws;

    __bf16* QT = (__bf16*)(wsb + QT_OFF);
    __bf16* KT = (__bf16*)(wsb + KT_OFF);
    __bf16* VB = (__bf16*)(wsb + VB_OFF);
    __bf16* AT = (__bf16*)(wsb + AT_OFF);
    float*  A1 = (float*)(wsb + A1_OFF);
    float*  A2 = (float*)(wsb + A2_OFF);
    float*  HB = (float*)(wsb + HB_OFF);
    float*  MR = (float*)(wsb + MR_OFF);
    float*  IS = (float*)(wsb + IS_OFF);
    float*  G0 = (float*)(wsb + G0_OFF);
    float*  EC = (float*)(wsb + EC_OFF);
    float*  P4 = EC;   // conv partials reuse E-chunk space (after attention done)

    (void)in_sizes; (void)n_in; (void)out_size;

    long nb = ((long)ws_size - (long)EC_OFF) / (long)EC_CHUNK;
    if (nb < 1) nb = 1;
    if (nb > 8) nb = 8;

    for (int a = 0; a < 2; ++a) {
        const float* Xq  = (a == 0) ? x1 : x2;
        const float* Xkv = (a == 0) ? x2 : x1;
        const float* wq  = (a == 0) ? wq1 : wq2;
        const float* wk  = (a == 0) ? wk1 : wk2;
        const float* wv  = (a == 0) ? wv1 : wv2;
        const float* bv  = (a == 0) ? bv1 : bv2;
        const float* gm  = (a == 0) ? g1  : g2;
        float* A         = (a == 0) ? A1  : A2;
        const int aoff   = (a == 0) ? 0   : CH;

        proj3_mfma<<<dim3(18, 2, 24), 256, 0, stream>>>(
            Xq, Xkv, wq, wk, wv, bv, QT, KT, VB);

        for (int bofs = 0; bofs < BATCH; bofs += (int)nb) {
            const int nbc = ((int)nb < BATCH - bofs) ? (int)nb : (BATCH - bofs);
            energy_mfma<<<dim3(18, 18, nbc), 256, 0, stream>>>(QT, KT, EC, bofs);
            rowstat_kernel<<<dim3(nbc * HW), 256, 0, stream>>>(EC, MR, IS, bofs);
            pv2_mfma<<<dim3(18, 2, nbc), 256, 0, stream>>>(
                VB, EC, MR, IS, Xq, gm, A, AT, aoff, bofs);
        }
    }

    conv1_mfma<<<dim3(18, 4, 8), 256, 0, stream>>>(AT, fw1, P4);
    reduce_hb<<<dim3(4608), 256, 0, stream>>>(P4, fb1, HB);
    gates_kernel<<<dim3(72), 256, 0, stream>>>(HB, fw2, fb2, G0);
    blend_kernel<<<dim3(4608), 256, 0, stream>>>(A1, A2, G0, out);
}

// Round 4
// 696.100 us; speedup vs baseline: 3.9573x; 1.0838x over previous
//
#include <hip/hip_runtime.h>

namespace {

constexpr int BATCH = 8;
constexpr int CH    = 256;   // C
constexpr int HW    = 2304;  // 48*48
constexpr int IMG   = 48;
constexpr int CG    = 64;

typedef __bf16 bf16x8 __attribute__((ext_vector_type(8)));
typedef __bf16 bf16x4 __attribute__((ext_vector_type(4)));
typedef float  f32x4  __attribute__((ext_vector_type(4)));

constexpr int ROWB = 40;    // LDS row stride (bf16) for 32-wide K-chunk tiles
constexpr int PSTR = 136;   // P_lds row stride (bf16), 128 data + 8 pad
constexpr int KSTR = 136;   // stats K-tile stride (bf16), 128 data + 8 pad
constexpr int CSTR = 40;    // conv LDS stride

// ---- ws layout (bytes) ----
constexpr size_t BF_SLAB = (size_t)BATCH * HW * CH * 2;      // 9,437,184
constexpr size_t QT1_OFF = 0;
constexpr size_t KT1_OFF = 1 * BF_SLAB;
constexpr size_t VB1_OFF = 2 * BF_SLAB;
constexpr size_t QT2_OFF = 3 * BF_SLAB;
constexpr size_t KT2_OFF = 4 * BF_SLAB;
constexpr size_t VB2_OFF = 5 * BF_SLAB;
constexpr size_t AT_OFF  = 6 * BF_SLAB;                      // bf16 [B][HW][512]
constexpr size_t A1_OFF  = AT_OFF + (size_t)BATCH * HW * 512 * 2;
constexpr size_t A2_OFF  = A1_OFF + (size_t)BATCH * CH * HW * 4;
constexpr size_t HB_OFF  = A2_OFF + (size_t)BATCH * CH * HW * 4;
constexpr size_t M_OFF   = HB_OFF + (size_t)BATCH * CG * HW * 4;
constexpr size_t IS_OFF  = M_OFF  + (size_t)2 * BATCH * HW * 4;
constexpr size_t G0_OFF  = IS_OFF + (size_t)2 * BATCH * HW * 4;
constexpr size_t WT_OFF  = G0_OFF + (size_t)BATCH * HW * 4;
// end = WT_OFF + 589,824 = 118,923,264 B  (<= 120.5 MB proven available)
// P4 (conv partials, 18.87 MB) aliases QT1/KT1 slabs (free after attention).

// stage 16 bf16 elems/thread from row-major src into [128][ROWB] LDS
__device__ __forceinline__ void stage_bf16(const __bf16* __restrict__ src, size_t srcStride,
                                           __bf16* dst, int t) {
    const int r = t & 127, s = t >> 7;
    const bf16x8* sp = reinterpret_cast<const bf16x8*>(src + (size_t)r * srcStride + s * 16);
    bf16x8* dp = reinterpret_cast<bf16x8*>(dst + r * ROWB + s * 16);
    dp[0] = sp[0];
    dp[1] = sp[1];
}

// stage 16 fp32 elems/thread (convert to bf16) into [128][ROWB] LDS
__device__ __forceinline__ void stage_f32(const float* __restrict__ src, size_t srcStride,
                                          __bf16* dst, int t) {
    const int r = t & 127, s = t >> 7;
    const float4* sp = reinterpret_cast<const float4*>(src + (size_t)r * srcStride + s * 16);
    float4 f0 = sp[0], f1 = sp[1], f2 = sp[2], f3 = sp[3];
    bf16x8 v0, v1;
    v0[0]=(__bf16)f0.x; v0[1]=(__bf16)f0.y; v0[2]=(__bf16)f0.z; v0[3]=(__bf16)f0.w;
    v0[4]=(__bf16)f1.x; v0[5]=(__bf16)f1.y; v0[6]=(__bf16)f1.z; v0[7]=(__bf16)f1.w;
    v1[0]=(__bf16)f2.x; v1[1]=(__bf16)f2.y; v1[2]=(__bf16)f2.z; v1[3]=(__bf16)f2.w;
    v1[4]=(__bf16)f3.x; v1[5]=(__bf16)f3.y; v1[6]=(__bf16)f3.z; v1[7]=(__bf16)f3.w;
    bf16x8* dp = reinterpret_cast<bf16x8*>(dst + r * ROWB + s * 16);
    dp[0] = v0;
    dp[1] = v1;
}

// 4-wave 128x128 MFMA step: wave (wm,wn) owns 64x64; 16 mfma  [proven round 3]
__device__ __forceinline__ void frag_step(const __bf16* As, const __bf16* Bs,
                                          f32x4 (&acc)[4][4], int lane, int wm, int wn) {
    const int r = lane & 15, g = lane >> 4;
    bf16x8 a[4], b[4];
#pragma unroll
    for (int i = 0; i < 4; ++i) {
        a[i] = *reinterpret_cast<const bf16x8*>(As + (wm * 64 + i * 16 + r) * ROWB + g * 8);
        b[i] = *reinterpret_cast<const bf16x8*>(Bs + (wn * 64 + i * 16 + r) * ROWB + g * 8);
    }
#pragma unroll
    for (int i = 0; i < 4; ++i)
#pragma unroll
        for (int j = 0; j < 4; ++j)
            acc[i][j] = __builtin_amdgcn_mfma_f32_16x16x32_bf16(a[i], b[j], acc[i][j], 0, 0, 0);
}

// ---------------------------------------------------------------------------
// proj3: Q/K/V for one attention. Q,K TRANSPOSED bf16 [B][HW][256]; V [B][256][HW].
// [proven round 3 verbatim]
__global__ __launch_bounds__(256) void proj3_mfma(
    const float* __restrict__ Xsrc, const float* __restrict__ Xg,
    const float* __restrict__ wq, const float* __restrict__ wk,
    const float* __restrict__ wv, const float* __restrict__ bv,
    __bf16* __restrict__ QT, __bf16* __restrict__ KT, __bf16* __restrict__ VB)
{
    __shared__ __bf16 As[128 * ROWB];
    __shared__ __bf16 Bs[128 * ROWB];
    const int p = blockIdx.z >> 3;      // 0=Q 1=K 2=V
    const int b = blockIdx.z & 7;
    const float* W = (p == 0) ? wq : (p == 1) ? wk : wv;
    const float* X = (p == 0) ? Xsrc : Xg;
    const float* Xb = X + (size_t)b * CH * HW;

    const int t = threadIdx.x;
    const int lane = t & 63, wid = t >> 6;
    const int wm = wid >> 1, wn = wid & 1;
    const int m0 = blockIdx.y * 128, n0 = blockIdx.x * 128;

    f32x4 acc[4][4] = {};
    const int nB = t & 127, halfB = t >> 7;

    for (int k0 = 0; k0 < CH; k0 += 32) {
        stage_f32(W + (size_t)m0 * CH + k0, CH, As, t);
        float v[16];
#pragma unroll
        for (int kk = 0; kk < 16; ++kk)
            v[kk] = Xb[(size_t)(k0 + halfB * 16 + kk) * HW + n0 + nB];
        bf16x8 p0, p1;
#pragma unroll
        for (int kk = 0; kk < 8; ++kk) { p0[kk] = (__bf16)v[kk]; p1[kk] = (__bf16)v[kk + 8]; }
        bf16x8* dp = reinterpret_cast<bf16x8*>(Bs + nB * ROWB + halfB * 16);
        dp[0] = p0; dp[1] = p1;
        __syncthreads();
        frag_step(As, Bs, acc, lane, wm, wn);
        __syncthreads();
    }

    const int g = lane >> 4, r = lane & 15;
    if (p < 2) {
        __bf16* T = (p == 0) ? QT : KT;
#pragma unroll
        for (int mi = 0; mi < 4; ++mi)
#pragma unroll
            for (int nj = 0; nj < 4; ++nj) {
                const int mb = m0 + wm * 64 + mi * 16 + g * 4;
                const int n  = n0 + wn * 64 + nj * 16 + r;
                bf16x4 pk;
#pragma unroll
                for (int q = 0; q < 4; ++q) pk[q] = (__bf16)acc[mi][nj][q];
                *reinterpret_cast<bf16x4*>(T + ((size_t)b * HW + n) * CH + mb) = pk;
            }
    } else {
#pragma unroll
        for (int mi = 0; mi < 4; ++mi)
#pragma unroll
            for (int nj = 0; nj < 4; ++nj) {
                const int mb = m0 + wm * 64 + mi * 16 + g * 4;
                const int n  = n0 + wn * 64 + nj * 16 + r;
#pragma unroll
                for (int q = 0; q < 4; ++q)
                    VB[((size_t)b * CH + mb + q) * HW + n] = (__bf16)(acc[mi][nj][q] + bv[mb + q]);
            }
    }
}

// ---------------------------------------------------------------------------
// stats: per softmax row (Q row), M = max_j S, IS = 1/sum exp(S-M). No E store.
// grid (36 i-tiles of 64 rows, 16 z = att*8+b), block 256 (4 waves x 16 rows).
__global__ __launch_bounds__(256, 2) void stats_mfma(
    const __bf16* __restrict__ QT1, const __bf16* __restrict__ KT1,
    const __bf16* __restrict__ QT2, const __bf16* __restrict__ KT2,
    float* __restrict__ M, float* __restrict__ IS)
{
    __shared__ __bf16 Ks[128 * KSTR];
    const int z = blockIdx.y;
    const int att = z >> 3, b = z & 7;
    const __bf16* QT = att ? QT2 : QT1;
    const __bf16* KT = att ? KT2 : KT1;
    const int i0 = blockIdx.x * 64;
    const int t = threadIdx.x, lane = t & 63, wid = t >> 6;
    const int r = lane & 15, g = lane >> 4;

    // Q fragments in registers: this lane's row, all 8 k-chunks
    bf16x8 qf[8];
    {
        const __bf16* qrow = QT + ((size_t)b * HW + i0 + wid * 16 + r) * CH;
#pragma unroll
        for (int kc = 0; kc < 8; ++kc)
            qf[kc] = *reinterpret_cast<const bf16x8*>(qrow + kc * 32 + g * 8);
    }

    float m_run[4] = {-3.0e38f, -3.0e38f, -3.0e38f, -3.0e38f};
    float s_run[4] = {0.f, 0.f, 0.f, 0.f};

    const int rr = t & 127, cblk = (t >> 7) * 64;

    for (int j0 = 0; j0 < HW; j0 += 128) {
        f32x4 acc[8] = {};
#pragma unroll 1
        for (int kh = 0; kh < 2; ++kh) {
            // stage half of K-tile: 128 rows x 128 k
            {
                const __bf16* sp = KT + ((size_t)b * HW + j0 + rr) * CH + kh * 128 + cblk;
                __bf16* dp = Ks + rr * KSTR + cblk;
#pragma unroll
                for (int u = 0; u < 8; ++u)
                    *reinterpret_cast<bf16x8*>(dp + u * 8) =
                        *reinterpret_cast<const bf16x8*>(sp + u * 8);
            }
            __syncthreads();
#pragma unroll
            for (int kc = 0; kc < 4; ++kc) {
                bf16x8 bf[8];
#pragma unroll
                for (int j = 0; j < 8; ++j)
                    bf[j] = *reinterpret_cast<const bf16x8*>(Ks + (j * 16 + r) * KSTR + kc * 32 + g * 8);
#pragma unroll
                for (int j = 0; j < 8; ++j)
                    acc[j] = __builtin_amdgcn_mfma_f32_16x16x32_bf16(qf[kh * 4 + kc], bf[j], acc[j], 0, 0, 0);
            }
            __syncthreads();
        }
        // online stats update (per q-row of this lane's group)
#pragma unroll
        for (int q = 0; q < 4; ++q) {
            float tmax = acc[0][q];
#pragma unroll
            for (int j = 1; j < 8; ++j) tmax = fmaxf(tmax, acc[j][q]);
            tmax = fmaxf(tmax, __shfl_xor(tmax, 1));
            tmax = fmaxf(tmax, __shfl_xor(tmax, 2));
            tmax = fmaxf(tmax, __shfl_xor(tmax, 4));
            tmax = fmaxf(tmax, __shfl_xor(tmax, 8));
            const float nm = fmaxf(m_run[q], tmax);
            float ts = 0.f;
#pragma unroll
            for (int j = 0; j < 8; ++j) ts += __expf(acc[j][q] - nm);
            ts += __shfl_xor(ts, 1);
            ts += __shfl_xor(ts, 2);
            ts += __shfl_xor(ts, 4);
            ts += __shfl_xor(ts, 8);
            s_run[q] = s_run[q] * __expf(m_run[q] - nm) + ts;
            m_run[q] = nm;
        }
    }
    if (r == 0) {
#pragma unroll
        for (int q = 0; q < 4; ++q) {
            const size_t gi = (size_t)z * HW + i0 + wid * 16 + g * 4 + q;
            M[gi]  = m_run[q];
            IS[gi] = 1.f / s_run[q];
        }
    }
}

// ---------------------------------------------------------------------------
// fused PV: recompute S tile, P = exp(S - M[n]) (bf16, LDS), O += V*P; epilogue
// applies gamma*IS[n] + residual. grid (18 n-tiles, 2 c-halves, 16 z), block 256.
__global__ __launch_bounds__(256, 2) void fused_pv(
    const __bf16* __restrict__ QT1, const __bf16* __restrict__ KT1, const __bf16* __restrict__ VB1,
    const __bf16* __restrict__ QT2, const __bf16* __restrict__ KT2, const __bf16* __restrict__ VB2,
    const float* __restrict__ M, const float* __restrict__ IS,
    const float* __restrict__ x1, const float* __restrict__ x2,
    const float* __restrict__ g1, const float* __restrict__ g2,
    float* __restrict__ A1, float* __restrict__ A2, __bf16* __restrict__ AT)
{
    __shared__ __bf16 As[128 * ROWB];
    __shared__ __bf16 Bs[128 * ROWB];
    __shared__ __bf16 P_lds[128 * PSTR];

    const int z = blockIdx.z;
    const int att = z >> 3, b = z & 7;
    const __bf16* QT = att ? QT2 : QT1;
    const __bf16* KT = att ? KT2 : KT1;
    const __bf16* VB = att ? VB2 : VB1;
    const float* src = att ? x2 : x1;
    const float* gmp = att ? g2 : g1;
    float* A         = att ? A2 : A1;
    const int aoff   = att ? CH : 0;

    const int t = threadIdx.x, lane = t & 63, wid = t >> 6;
    const int wm = wid >> 1, wn = wid & 1;
    const int r = lane & 15, g = lane >> 4;
    const int n0 = blockIdx.x * 128, c0 = blockIdx.y * 128;

    // per-lane row maxima (16 rows this lane contributes to in S-phase)
    float M_l[16];
    {
        const float* Mp = M + (size_t)z * HW + n0 + wm * 64;
#pragma unroll
        for (int mi = 0; mi < 4; ++mi)
#pragma unroll
            for (int q = 0; q < 4; ++q)
                M_l[mi * 4 + q] = Mp[mi * 16 + g * 4 + q];
    }

    f32x4 accO[4][4] = {};

    for (int m0 = 0; m0 < HW; m0 += 128) {
        // ---- S phase: S[n0..+128][m0..+128] over K=256
        f32x4 accS[4][4] = {};
        for (int k0 = 0; k0 < CH; k0 += 32) {
            stage_bf16(QT + ((size_t)b * HW + n0) * CH + k0, CH, As, t);
            stage_bf16(KT + ((size_t)b * HW + m0) * CH + k0, CH, Bs, t);
            __syncthreads();
            frag_step(As, Bs, accS, lane, wm, wn);
            __syncthreads();
        }
        // ---- P = exp(S - M) -> LDS (bf16, unnormalized)
#pragma unroll
        for (int mi = 0; mi < 4; ++mi)
#pragma unroll
            for (int nj = 0; nj < 4; ++nj)
#pragma unroll
                for (int q = 0; q < 4; ++q) {
                    const float p = __expf(accS[mi][nj][q] - M_l[mi * 4 + q]);
                    P_lds[(wm * 64 + mi * 16 + g * 4 + q) * PSTR + wn * 64 + nj * 16 + r] = (__bf16)p;
                }
        __syncthreads();
        // ---- PV phase: O[c][n] += V[c][m-chunk] * P[n][m-chunk]
#pragma unroll 1
        for (int kc = 0; kc < 4; ++kc) {
            stage_bf16(VB + ((size_t)b * CH + c0) * HW + m0 + kc * 32, HW, As, t);
            __syncthreads();
            bf16x8 av[4], bp[4];
#pragma unroll
            for (int i = 0; i < 4; ++i)
                av[i] = *reinterpret_cast<const bf16x8*>(As + (wm * 64 + i * 16 + r) * ROWB + g * 8);
#pragma unroll
            for (int j = 0; j < 4; ++j)
                bp[j] = *reinterpret_cast<const bf16x8*>(P_lds + (wn * 64 + j * 16 + r) * PSTR + kc * 32 + g * 8);
#pragma unroll
            for (int i = 0; i < 4; ++i)
#pragma unroll
                for (int j = 0; j < 4; ++j)
                    accO[i][j] = __builtin_amdgcn_mfma_f32_16x16x32_bf16(av[i], bp[j], accO[i][j], 0, 0, 0);
            __syncthreads();
        }
    }

    // ---- epilogue: val = gamma * IS[n] * O + src
    const float gm = gmp[0];
    float IS_l[4];
#pragma unroll
    for (int j = 0; j < 4; ++j)
        IS_l[j] = IS[(size_t)z * HW + n0 + wn * 64 + j * 16 + r];
#pragma unroll
    for (int mi = 0; mi < 4; ++mi)
#pragma unroll
        for (int nj = 0; nj < 4; ++nj) {
            const int cb = c0 + wm * 64 + mi * 16 + g * 4;
            const int n  = n0 + wn * 64 + nj * 16 + r;
            const float sc = gm * IS_l[nj];
            float vals[4];
#pragma unroll
            for (int q = 0; q < 4; ++q) {
                const size_t idx = ((size_t)b * CH + cb + q) * HW + n;
                vals[q] = sc * accO[mi][nj][q] + src[idx];
                A[idx] = vals[q];
            }
            bf16x4 pk;
#pragma unroll
            for (int q = 0; q < 4; ++q) pk[q] = (__bf16)vals[q];
            *reinterpret_cast<bf16x4*>(AT + ((size_t)b * HW + n) * 512 + aoff + cb) = pk;
        }
}

// ---------------------------------------------------------------------------
// wprep: fw1 [64][512*9] fp32 -> WT bf16 [tap][m][512]
__global__ __launch_bounds__(256) void wprep(const float* __restrict__ fw1,
                                             __bf16* __restrict__ WT)
{
    const int i = blockIdx.x * 256 + threadIdx.x;   // 9*64*512 = 294912 exact
    const int tap = i >> 15;            // /(64*512)
    const int rem = i & 32767;
    const int m = rem >> 9, c = rem & 511;
    WT[i] = (__bf16)fw1[(size_t)m * 4608 + c * 9 + tap];
}

// ---------------------------------------------------------------------------
// conv1 v2: 3x3 conv (512->64), K split 4-way across blocks, halo-staged pixels.
// grid (18 n-tiles, 4 kc, 8 b), block 256 (4 waves x 32 n each).
__global__ __launch_bounds__(256) void conv1_v2(
    const __bf16* __restrict__ AT, const __bf16* __restrict__ WT,
    float* __restrict__ P4)
{
    __shared__ __bf16 A9[9 * 64 * CSTR];     // 46080 B
    __shared__ __bf16 HALO[240 * CSTR];      // 19200 B (rows n0-56 .. n0+183)
    const int kc = blockIdx.y, b = blockIdx.z, n0 = blockIdx.x * 128;
    const int t = threadIdx.x, lane = t & 63, wid = t >> 6;
    const int r = lane & 15, g = lane >> 4;

    int yj[2], xj[2];
#pragma unroll
    for (int j = 0; j < 2; ++j) {
        const int p = n0 + wid * 32 + j * 16 + r;
        yj[j] = p / IMG; xj[j] = p - yj[j] * IMG;
    }

    f32x4 acc[4][2] = {};

#pragma unroll 1
    for (int st = 0; st < 4; ++st) {
        const int cbase = kc * 128 + st * 32;
        // stage halo: 240 rows x 32 channels
        if (t < 240) {
            const int nn = n0 - 56 + t;
            bf16x8 h0 = {}, h1 = {}, h2 = {}, h3 = {};
            if (nn >= 0 && nn < HW) {
                const bf16x8* sp = reinterpret_cast<const bf16x8*>(
                    AT + ((size_t)b * HW + nn) * 512 + cbase);
                h0 = sp[0]; h1 = sp[1]; h2 = sp[2]; h3 = sp[3];
            }
            bf16x8* dp = reinterpret_cast<bf16x8*>(HALO + t * CSTR);
            dp[0] = h0; dp[1] = h1; dp[2] = h2; dp[3] = h3;
        }
        // stage 9 weight tiles [64][32]
        {
            const int m = t >> 2, seg = t & 3;
#pragma unroll
            for (int tap = 0; tap < 9; ++tap)
                *reinterpret_cast<bf16x8*>(A9 + (tap * 64 + m) * CSTR + seg * 8) =
                    *reinterpret_cast<const bf16x8*>(WT + ((size_t)tap * 64 + m) * 512 + cbase + seg * 8);
        }
        __syncthreads();
#pragma unroll 1
        for (int tap = 0; tap < 9; ++tap) {
            const int dy = tap / 3 - 1;
            const int dx = tap - (tap / 3) * 3 - 1;
            bf16x8 bb[2];
#pragma unroll
            for (int j = 0; j < 2; ++j) {
                const bool valid = ((unsigned)(yj[j] + dy) < (unsigned)IMG) &&
                                   ((unsigned)(xj[j] + dx) < (unsigned)IMG);
                const int row = wid * 32 + j * 16 + r + 56 + dy * IMG + dx;
                bf16x8 v = {};
                if (valid) v = *reinterpret_cast<const bf16x8*>(HALO + row * CSTR + g * 8);
                bb[j] = v;
            }
            bf16x8 a[4];
#pragma unroll
            for (int i = 0; i < 4; ++i)
                a[i] = *reinterpret_cast<const bf16x8*>(A9 + (tap * 64 + i * 16 + r) * CSTR + g * 8);
#pragma unroll
            for (int i = 0; i < 4; ++i)
#pragma unroll
                for (int j = 0; j < 2; ++j)
                    acc[i][j] = __builtin_amdgcn_mfma_f32_16x16x32_bf16(a[i], bb[j], acc[i][j], 0, 0, 0);
        }
        __syncthreads();
    }
#pragma unroll
    for (int mi = 0; mi < 4; ++mi)
#pragma unroll
        for (int nj = 0; nj < 2; ++nj) {
            const int m = mi * 16 + g * 4;
            const int n = n0 + wid * 32 + nj * 16 + r;
#pragma unroll
            for (int q = 0; q < 4; ++q)
                P4[(((size_t)kc * BATCH + b) * CG + m + q) * HW + n] = acc[mi][nj][q];
        }
}

// ---------------------------------------------------------------------------
__global__ __launch_bounds__(256) void reduce_hb(
    const float* __restrict__ P4, const float* __restrict__ fb1,
    float* __restrict__ HB)
{
    const int idx = blockIdx.x * 256 + threadIdx.x;     // 8*64*2304 exactly
    constexpr size_t STRIDE = (size_t)BATCH * CG * HW;
    const int m = (idx / HW) & 63;
    float s = P4[idx] + P4[idx + STRIDE] + P4[idx + 2 * STRIDE] + P4[idx + 3 * STRIDE];
    HB[idx] = fmaxf(s + fb1[m], 0.f);
}

// ---------------------------------------------------------------------------
// gates v2: 288 blocks; 64 pixels/block, channels split 4-way + LDS reduce.
__global__ __launch_bounds__(256) void gates_v2(
    const float* __restrict__ hbuf, const float* __restrict__ fw2,
    const float* __restrict__ fb2, float* __restrict__ g0buf)
{
    __shared__ float w2s[1152];
    __shared__ float par[2][4][64];
    const int t = threadIdx.x;
    for (int i = t; i < 1152; i += 256) w2s[i] = fw2[i];
    __syncthreads();
    const int px = t & 63, grp = t >> 6;
    const int idx = blockIdx.x * 64 + px;
    const int b = idx / HW;
    const int n = idx - b * HW;
    const int y = n / IMG, x = n - (n / IMG) * IMG;
    float c0 = 0.f, c1 = 0.f;
    const float* hb = hbuf + ((size_t)b * CG + grp * 16) * HW;
    for (int ci = 0; ci < 16; ++ci) {
        const float* hp = hb + (size_t)ci * HW;
        const float* w0 = &w2s[(grp * 16 + ci) * 9];
        const float* w1 = &w2s[576 + (grp * 16 + ci) * 9];
#pragma unroll
        for (int tap = 0; tap < 9; ++tap) {
            const int dy = tap / 3 - 1, dx = tap % 3 - 1;
            const int yy = y + dy, xx = x + dx;
            if (yy >= 0 && yy < IMG && xx >= 0 && xx < IMG) {
                const float hv = hp[yy * IMG + xx];
                c0 = fmaf(hv, w0[tap], c0);
                c1 = fmaf(hv, w1[tap], c1);
            }
        }
    }
    par[0][grp][px] = c0;
    par[1][grp][px] = c1;
    __syncthreads();
    if (t < 64) {
        const float s0 = par[0][0][t] + par[0][1][t] + par[0][2][t] + par[0][3][t] + fb2[0];
        const float s1 = par[1][0][t] + par[1][1][t] + par[1][2][t] + par[1][3][t] + fb2[1];
        g0buf[blockIdx.x * 64 + t] = 1.f / (1.f + __expf(s1 - s0));
    }
}

// ---------------------------------------------------------------------------
__global__ __launch_bounds__(256) void blend_kernel(
    const float* __restrict__ att1, const float* __restrict__ att2,
    const float* __restrict__ g0buf, float* __restrict__ out)
{
    const int i = blockIdx.x * 256 + threadIdx.x;
    const int r = i / 576;
    const int q = i - r * 576;
    const int b = r >> 8;
    const float4 a1 = reinterpret_cast<const float4*>(att1)[i];
    const float4 a2 = reinterpret_cast<const float4*>(att2)[i];
    const float4 g  = *reinterpret_cast<const float4*>(&g0buf[(size_t)b * HW + q * 4]);
    float4 o;
    o.x = g.x * a1.x + (1.f - g.x) * a2.x;
    o.y = g.y * a1.y + (1.f - g.y) * a2.y;
    o.z = g.z * a1.z + (1.f - g.z) * a2.z;
    o.w = g.w * a1.w + (1.f - g.w) * a2.w;
    reinterpret_cast<float4*>(out)[i] = o;
}

} // namespace

extern "C" void kernel_launch(void* const* d_in, const int* in_sizes, int n_in,
                              void* d_out, int out_size, void* d_ws, size_t ws_size,
                              hipStream_t stream)
{
    const float* x1  = (const float*)d_in[0];
    const float* x2  = (const float*)d_in[1];
    const float* wq1 = (const float*)d_in[2];
    const float* wk1 = (const float*)d_in[3];
    const float* wv1 = (const float*)d_in[4];
    const float* bv1 = (const float*)d_in[5];
    const float* g1  = (const float*)d_in[6];
    const float* wq2 = (const float*)d_in[7];
    const float* wk2 = (const float*)d_in[8];
    const float* wv2 = (const float*)d_in[9];
    const float* bv2 = (const float*)d_in[10];
    const float* g2  = (const float*)d_in[11];
    const float* fw1 = (const float*)d_in[12];
    const float* fb1 = (const float*)d_in[13];
    const float* fw2 = (const float*)d_in[14];
    const float* fb2 = (const float*)d_in[15];
    float* out = (float*)d_out;
    char*  wsb = (char*)d_ws;

    __bf16* QT1 = (__bf16*)(wsb + QT1_OFF);
    __bf16* KT1 = (__bf16*)(wsb + KT1_OFF);
    __bf16* VB1 = (__bf16*)(wsb + VB1_OFF);
    __bf16* QT2 = (__bf16*)(wsb + QT2_OFF);
    __bf16* KT2 = (__bf16*)(wsb + KT2_OFF);
    __bf16* VB2 = (__bf16*)(wsb + VB2_OFF);
    __bf16* AT  = (__bf16*)(wsb + AT_OFF);
    float*  A1  = (float*)(wsb + A1_OFF);
    float*  A2  = (float*)(wsb + A2_OFF);
    float*  HB  = (float*)(wsb + HB_OFF);
    float*  MR  = (float*)(wsb + M_OFF);
    float*  IS  = (float*)(wsb + IS_OFF);
    float*  G0  = (float*)(wsb + G0_OFF);
    __bf16* WT  = (__bf16*)(wsb + WT_OFF);
    float*  P4  = (float*)(wsb + QT1_OFF);   // alias: free after attention

    (void)in_sizes; (void)n_in; (void)out_size; (void)ws_size;

    proj3_mfma<<<dim3(18, 2, 24), 256, 0, stream>>>(x1, x2, wq1, wk1, wv1, bv1, QT1, KT1, VB1);
    proj3_mfma<<<dim3(18, 2, 24), 256, 0, stream>>>(x2, x1, wq2, wk2, wv2, bv2, QT2, KT2, VB2);
    wprep<<<dim3(1152), 256, 0, stream>>>(fw1, WT);

    stats_mfma<<<dim3(36, 16), 256, 0, stream>>>(QT1, KT1, QT2, KT2, MR, IS);

    fused_pv<<<dim3(18, 2, 16), 256, 0, stream>>>(
        QT1, KT1, VB1, QT2, KT2, VB2, MR, IS, x1, x2, g1, g2, A1, A2, AT);

    conv1_v2<<<dim3(18, 4, 8), 256, 0, stream>>>(AT, WT, P4);
    reduce_hb<<<dim3(4608), 256, 0, stream>>>(P4, fb1, HB);
    gates_v2<<<dim3(288), 256, 0, stream>>>(HB, fw2, fb2, G0);
    blend_kernel<<<dim3(4608), 256, 0, stream>>>(A1, A2, G0, out);
}

// Round 5
// 631.774 us; speedup vs baseline: 4.3603x; 1.1018x over previous
//
#include <hip/hip_runtime.h>

namespace {

constexpr int BATCH = 8;
constexpr int CH    = 256;   // C
constexpr int HW    = 2304;  // 48*48
constexpr int IMG   = 48;
constexpr int CG    = 64;

typedef __bf16 bf16x8 __attribute__((ext_vector_type(8)));
typedef __bf16 bf16x4 __attribute__((ext_vector_type(4)));
typedef float  f32x4  __attribute__((ext_vector_type(4)));

constexpr int ROWB = 40;    // LDS row stride (bf16) for 32-wide K-chunk tiles (proj)
constexpr int QSTR = 72;    // fused: Q/K/V LDS row stride (64 data + 8 pad)
constexpr int PSTR = 132;   // fused: P_lds row stride (128 data + 4 pad)
constexpr int CSTR = 40;    // conv LDS stride

// ---- ws layout (bytes) ----
constexpr size_t BF_SLAB = (size_t)BATCH * HW * CH * 2;      // 9,437,184
constexpr size_t QT1_OFF = 0;
constexpr size_t KT1_OFF = 1 * BF_SLAB;
constexpr size_t VB1_OFF = 2 * BF_SLAB;
constexpr size_t QT2_OFF = 3 * BF_SLAB;
constexpr size_t KT2_OFF = 4 * BF_SLAB;
constexpr size_t VB2_OFF = 5 * BF_SLAB;
constexpr size_t AT_OFF  = 6 * BF_SLAB;                      // bf16 [B][HW][512]
constexpr size_t A1_OFF  = AT_OFF + (size_t)BATCH * HW * 512 * 2;
constexpr size_t A2_OFF  = A1_OFF + (size_t)BATCH * CH * HW * 4;
constexpr size_t HB_OFF  = A2_OFF + (size_t)BATCH * CH * HW * 4;
constexpr size_t G0_OFF  = HB_OFF + (size_t)BATCH * CG * HW * 4;
constexpr size_t WT_OFF  = G0_OFF + (size_t)BATCH * HW * 4;
// end = WT_OFF + 589,824 ~= 112 MB; P4 (conv partials) aliases QT1/KT1 slabs.

// stage 16 bf16 elems/thread from row-major src into [128][ROWB] LDS (256-thr blocks)
__device__ __forceinline__ void stage_bf16(const __bf16* __restrict__ src, size_t srcStride,
                                           __bf16* dst, int t) {
    const int r = t & 127, s = t >> 7;
    const bf16x8* sp = reinterpret_cast<const bf16x8*>(src + (size_t)r * srcStride + s * 16);
    bf16x8* dp = reinterpret_cast<bf16x8*>(dst + r * ROWB + s * 16);
    dp[0] = sp[0];
    dp[1] = sp[1];
}

// stage 16 fp32 elems/thread (convert to bf16) into [128][ROWB] LDS (256-thr blocks)
__device__ __forceinline__ void stage_f32(const float* __restrict__ src, size_t srcStride,
                                          __bf16* dst, int t) {
    const int r = t & 127, s = t >> 7;
    const float4* sp = reinterpret_cast<const float4*>(src + (size_t)r * srcStride + s * 16);
    float4 f0 = sp[0], f1 = sp[1], f2 = sp[2], f3 = sp[3];
    bf16x8 v0, v1;
    v0[0]=(__bf16)f0.x; v0[1]=(__bf16)f0.y; v0[2]=(__bf16)f0.z; v0[3]=(__bf16)f0.w;
    v0[4]=(__bf16)f1.x; v0[5]=(__bf16)f1.y; v0[6]=(__bf16)f1.z; v0[7]=(__bf16)f1.w;
    v1[0]=(__bf16)f2.x; v1[1]=(__bf16)f2.y; v1[2]=(__bf16)f2.z; v1[3]=(__bf16)f2.w;
    v1[4]=(__bf16)f3.x; v1[5]=(__bf16)f3.y; v1[6]=(__bf16)f3.z; v1[7]=(__bf16)f3.w;
    bf16x8* dp = reinterpret_cast<bf16x8*>(dst + r * ROWB + s * 16);
    dp[0] = v0;
    dp[1] = v1;
}

// 4-wave 128x128 MFMA step (proj): wave (wm,wn) owns 64x64; 16 mfma [proven r3]
__device__ __forceinline__ void frag_step(const __bf16* As, const __bf16* Bs,
                                          f32x4 (&acc)[4][4], int lane, int wm, int wn) {
    const int r = lane & 15, g = lane >> 4;
    bf16x8 a[4], b[4];
#pragma unroll
    for (int i = 0; i < 4; ++i) {
        a[i] = *reinterpret_cast<const bf16x8*>(As + (wm * 64 + i * 16 + r) * ROWB + g * 8);
        b[i] = *reinterpret_cast<const bf16x8*>(Bs + (wn * 64 + i * 16 + r) * ROWB + g * 8);
    }
#pragma unroll
    for (int i = 0; i < 4; ++i)
#pragma unroll
        for (int j = 0; j < 4; ++j)
            acc[i][j] = __builtin_amdgcn_mfma_f32_16x16x32_bf16(a[i], b[j], acc[i][j], 0, 0, 0);
}

// ---------------------------------------------------------------------------
// proj3: Q/K/V for one attention. Q,K TRANSPOSED bf16 [B][HW][256]; V [B][256][HW].
// [proven round 3/4 verbatim]
__global__ __launch_bounds__(256) void proj3_mfma(
    const float* __restrict__ Xsrc, const float* __restrict__ Xg,
    const float* __restrict__ wq, const float* __restrict__ wk,
    const float* __restrict__ wv, const float* __restrict__ bv,
    __bf16* __restrict__ QT, __bf16* __restrict__ KT, __bf16* __restrict__ VB)
{
    __shared__ __bf16 As[128 * ROWB];
    __shared__ __bf16 Bs[128 * ROWB];
    const int p = blockIdx.z >> 3;      // 0=Q 1=K 2=V
    const int b = blockIdx.z & 7;
    const float* W = (p == 0) ? wq : (p == 1) ? wk : wv;
    const float* X = (p == 0) ? Xsrc : Xg;
    const float* Xb = X + (size_t)b * CH * HW;

    const int t = threadIdx.x;
    const int lane = t & 63, wid = t >> 6;
    const int wm = wid >> 1, wn = wid & 1;
    const int m0 = blockIdx.y * 128, n0 = blockIdx.x * 128;

    f32x4 acc[4][4] = {};
    const int nB = t & 127, halfB = t >> 7;

    for (int k0 = 0; k0 < CH; k0 += 32) {
        stage_f32(W + (size_t)m0 * CH + k0, CH, As, t);
        float v[16];
#pragma unroll
        for (int kk = 0; kk < 16; ++kk)
            v[kk] = Xb[(size_t)(k0 + halfB * 16 + kk) * HW + n0 + nB];
        bf16x8 p0, p1;
#pragma unroll
        for (int kk = 0; kk < 8; ++kk) { p0[kk] = (__bf16)v[kk]; p1[kk] = (__bf16)v[kk + 8]; }
        bf16x8* dp = reinterpret_cast<bf16x8*>(Bs + nB * ROWB + halfB * 16);
        dp[0] = p0; dp[1] = p1;
        __syncthreads();
        frag_step(As, Bs, acc, lane, wm, wn);
        __syncthreads();
    }

    const int g = lane >> 4, r = lane & 15;
    if (p < 2) {
        __bf16* T = (p == 0) ? QT : KT;
#pragma unroll
        for (int mi = 0; mi < 4; ++mi)
#pragma unroll
            for (int nj = 0; nj < 4; ++nj) {
                const int mb = m0 + wm * 64 + mi * 16 + g * 4;
                const int n  = n0 + wn * 64 + nj * 16 + r;
                bf16x4 pk;
#pragma unroll
                for (int q = 0; q < 4; ++q) pk[q] = (__bf16)acc[mi][nj][q];
                *reinterpret_cast<bf16x4*>(T + ((size_t)b * HW + n) * CH + mb) = pk;
            }
    } else {
#pragma unroll
        for (int mi = 0; mi < 4; ++mi)
#pragma unroll
            for (int nj = 0; nj < 4; ++nj) {
                const int mb = m0 + wm * 64 + mi * 16 + g * 4;
                const int n  = n0 + wn * 64 + nj * 16 + r;
#pragma unroll
                for (int q = 0; q < 4; ++q)
                    VB[((size_t)b * CH + mb + q) * HW + n] = (__bf16)(acc[mi][nj][q] + bv[mb + q]);
            }
    }
}

// ---------------------------------------------------------------------------
// fused_pv3: 512-thread two-sweep attention. Block = (n-tile 128, z = att*8+b),
// full C=256. Sweep0: S over all m-tiles -> online (M, 1/sum) per row (LDS).
// Sweep1: S again -> P(LDS,bf16) -> PV accumulate; epilogue gamma*IS + residual.
__device__ __forceinline__ void s_phase64(
    const __bf16* __restrict__ QTn, const __bf16* __restrict__ KTm,
    __bf16* Qs, __bf16* Ks, f32x4 (&accS)[4][2],
    int t, int wm, int ws, int r, int g)
{
    const int r2 = t >> 2, s2 = t & 3;
    for (int k0 = 0; k0 < CH; k0 += 64) {
        {
            const bf16x8* sq = reinterpret_cast<const bf16x8*>(QTn + (size_t)r2 * CH + k0 + s2 * 16);
            bf16x8* dq = reinterpret_cast<bf16x8*>(Qs + r2 * QSTR + s2 * 16);
            dq[0] = sq[0]; dq[1] = sq[1];
            const bf16x8* sk = reinterpret_cast<const bf16x8*>(KTm + (size_t)r2 * CH + k0 + s2 * 16);
            bf16x8* dk = reinterpret_cast<bf16x8*>(Ks + r2 * QSTR + s2 * 16);
            dk[0] = sk[0]; dk[1] = sk[1];
        }
        __syncthreads();
#pragma unroll
        for (int kk = 0; kk < 2; ++kk) {
            bf16x8 a[4], bb[2];
#pragma unroll
            for (int i = 0; i < 4; ++i)
                a[i] = *reinterpret_cast<const bf16x8*>(Qs + (wm * 64 + i * 16 + r) * QSTR + kk * 32 + g * 8);
#pragma unroll
            for (int j = 0; j < 2; ++j)
                bb[j] = *reinterpret_cast<const bf16x8*>(Ks + (ws * 32 + j * 16 + r) * QSTR + kk * 32 + g * 8);
#pragma unroll
            for (int i = 0; i < 4; ++i)
#pragma unroll
                for (int j = 0; j < 2; ++j)
                    accS[i][j] = __builtin_amdgcn_mfma_f32_16x16x32_bf16(a[i], bb[j], accS[i][j], 0, 0, 0);
        }
        __syncthreads();
    }
}

__global__ __launch_bounds__(512) void fused_pv3(
    const __bf16* __restrict__ QT1, const __bf16* __restrict__ KT1, const __bf16* __restrict__ VB1,
    const __bf16* __restrict__ QT2, const __bf16* __restrict__ KT2, const __bf16* __restrict__ VB2,
    const float* __restrict__ x1, const float* __restrict__ x2,
    const float* __restrict__ g1, const float* __restrict__ g2,
    float* __restrict__ A1, float* __restrict__ A2, __bf16* __restrict__ AT)
{
    __shared__ __bf16 QK[2 * 128 * QSTR];    // Qs | Ks; Vs (256 rows) aliases both
    __shared__ __bf16 P_lds[128 * PSTR];     // also aliased as f32 scratch for stat combine
    __shared__ float  Mss[128];
    __shared__ float  ISs[128];
    __bf16* Qs = QK;
    __bf16* Ks = QK + 128 * QSTR;
    __bf16* Vs = QK;
    float*  red = reinterpret_cast<float*>(P_lds);

    // bijective XCD swizzle: group the 18 n-tiles of each z on one XCD (288 % 8 == 0)
    const int lid  = blockIdx.y * 18 + blockIdx.x;
    const int work = (lid & 7) * 36 + (lid >> 3);
    const int z = work / 18, ntile = work - z * 18;

    const int att = z >> 3, b = z & 7;
    const __bf16* QT = att ? QT2 : QT1;
    const __bf16* KT = att ? KT2 : KT1;
    const __bf16* VB = att ? VB2 : VB1;
    const float* src = att ? x2 : x1;
    const float* gmp = att ? g2 : g1;
    float* A         = att ? A2 : A1;
    const int aoff   = att ? CH : 0;

    const int t = threadIdx.x, lane = t & 63, wid = t >> 6;
    const int r = lane & 15, g = lane >> 4;
    const int wm = wid & 1, ws = wid >> 1;      // S roles: n-half, m-slice(32)
    const int wn2 = wid & 1, wc = wid >> 1;     // PV roles: n-half, c-chunk(64)
    const int n0 = ntile * 128;
    const __bf16* QTn = QT + ((size_t)b * HW + n0) * CH;

    // ---------------- sweep 0: stats ----------------
    {
        float m_run[16], s_run[16];
#pragma unroll
        for (int iq = 0; iq < 16; ++iq) { m_run[iq] = -3.0e38f; s_run[iq] = 0.f; }

        for (int m0 = 0; m0 < HW; m0 += 128) {
            f32x4 accS[4][2] = {};
            s_phase64(QTn, KT + ((size_t)b * HW + m0) * CH, Qs, Ks, accS, t, wm, ws, r, g);
#pragma unroll
            for (int i = 0; i < 4; ++i)
#pragma unroll
                for (int q = 0; q < 4; ++q) {
                    const int iq = i * 4 + q;
                    float tmax = fmaxf(accS[i][0][q], accS[i][1][q]);
                    tmax = fmaxf(tmax, __shfl_xor(tmax, 1));
                    tmax = fmaxf(tmax, __shfl_xor(tmax, 2));
                    tmax = fmaxf(tmax, __shfl_xor(tmax, 4));
                    tmax = fmaxf(tmax, __shfl_xor(tmax, 8));
                    const float nm = fmaxf(m_run[iq], tmax);
                    float ts = __expf(accS[i][0][q] - nm) + __expf(accS[i][1][q] - nm);
                    ts += __shfl_xor(ts, 1);
                    ts += __shfl_xor(ts, 2);
                    ts += __shfl_xor(ts, 4);
                    ts += __shfl_xor(ts, 8);
                    s_run[iq] = s_run[iq] * __expf(m_run[iq] - nm) + ts;
                    m_run[iq] = nm;
                }
        }
        // cross-wave combine (4 ws partials per row)
        if (r == 0) {
#pragma unroll
            for (int i = 0; i < 4; ++i)
#pragma unroll
                for (int q = 0; q < 4; ++q) {
                    const int row = wm * 64 + i * 16 + g * 4 + q;
                    red[row * 8 + ws * 2 + 0] = m_run[i * 4 + q];
                    red[row * 8 + ws * 2 + 1] = s_run[i * 4 + q];
                }
        }
        __syncthreads();
        if (t < 128) {
            float mv[4], sv[4];
#pragma unroll
            for (int w = 0; w < 4; ++w) { mv[w] = red[t * 8 + w * 2]; sv[w] = red[t * 8 + w * 2 + 1]; }
            float M = fmaxf(fmaxf(mv[0], mv[1]), fmaxf(mv[2], mv[3]));
            float S = sv[0] * __expf(mv[0] - M) + sv[1] * __expf(mv[1] - M) +
                      sv[2] * __expf(mv[2] - M) + sv[3] * __expf(mv[3] - M);
            Mss[t] = M;
            ISs[t] = 1.f / S;
        }
        __syncthreads();
    }

    // ---------------- sweep 1: S -> P -> PV ----------------
    f32x4 accO[4][4] = {};
    for (int m0 = 0; m0 < HW; m0 += 128) {
        f32x4 accS[4][2] = {};
        s_phase64(QTn, KT + ((size_t)b * HW + m0) * CH, Qs, Ks, accS, t, wm, ws, r, g);
        // P = exp(S - M) (bf16, unnormalized)
#pragma unroll
        for (int i = 0; i < 4; ++i)
#pragma unroll
            for (int j = 0; j < 2; ++j)
#pragma unroll
                for (int q = 0; q < 4; ++q) {
                    const int row = wm * 64 + i * 16 + g * 4 + q;
                    P_lds[row * PSTR + ws * 32 + j * 16 + r] =
                        (__bf16)__expf(accS[i][j][q] - Mss[row]);
                }
        // PV over the 128-m tile in two 64-wide chunks
#pragma unroll 1
        for (int kc = 0; kc < 2; ++kc) {
            {
                const int r3 = t >> 1, s3 = t & 1;
                const bf16x8* sv = reinterpret_cast<const bf16x8*>(
                    VB + ((size_t)b * CH + r3) * HW + m0 + kc * 64 + s3 * 32);
                bf16x8* dv = reinterpret_cast<bf16x8*>(Vs + r3 * QSTR + s3 * 32);
                dv[0] = sv[0]; dv[1] = sv[1]; dv[2] = sv[2]; dv[3] = sv[3];
            }
            __syncthreads();
#pragma unroll
            for (int kk = 0; kk < 2; ++kk) {
                bf16x8 a[4], bp[4];
#pragma unroll
                for (int i = 0; i < 4; ++i)
                    a[i] = *reinterpret_cast<const bf16x8*>(Vs + (wc * 64 + i * 16 + r) * QSTR + kk * 32 + g * 8);
#pragma unroll
                for (int j = 0; j < 4; ++j)
                    bp[j] = *reinterpret_cast<const bf16x8*>(P_lds + (wn2 * 64 + j * 16 + r) * PSTR + kc * 64 + kk * 32 + g * 8);
#pragma unroll
                for (int i = 0; i < 4; ++i)
#pragma unroll
                    for (int j = 0; j < 4; ++j)
                        accO[i][j] = __builtin_amdgcn_mfma_f32_16x16x32_bf16(a[i], bp[j], accO[i][j], 0, 0, 0);
            }
            __syncthreads();
        }
    }

    // ---------------- epilogue ----------------
    const float gm = gmp[0];
    float IS_l[4];
#pragma unroll
    for (int j = 0; j < 4; ++j)
        IS_l[j] = ISs[wn2 * 64 + j * 16 + r];
#pragma unroll
    for (int i = 0; i < 4; ++i)
#pragma unroll
        for (int j = 0; j < 4; ++j) {
            const int cb = wc * 64 + i * 16 + g * 4;
            const int n  = n0 + wn2 * 64 + j * 16 + r;
            const float sc = gm * IS_l[j];
            float vals[4];
#pragma unroll
            for (int q = 0; q < 4; ++q) {
                const size_t idx = ((size_t)b * CH + cb + q) * HW + n;
                vals[q] = sc * accO[i][j][q] + src[idx];
                A[idx] = vals[q];
            }
            bf16x4 pk;
#pragma unroll
            for (int q = 0; q < 4; ++q) pk[q] = (__bf16)vals[q];
            *reinterpret_cast<bf16x4*>(AT + ((size_t)b * HW + n) * 512 + aoff + cb) = pk;
        }
}

// ---------------------------------------------------------------------------
// wprep: fw1 [64][512*9] fp32 -> WT bf16 [tap][m][512]
__global__ __launch_bounds__(256) void wprep(const float* __restrict__ fw1,
                                             __bf16* __restrict__ WT)
{
    const int i = blockIdx.x * 256 + threadIdx.x;   // 9*64*512 = 294912 exact
    const int tap = i >> 15;
    const int rem = i & 32767;
    const int m = rem >> 9, c = rem & 511;
    WT[i] = (__bf16)fw1[(size_t)m * 4608 + c * 9 + tap];
}

// ---------------------------------------------------------------------------
// conv1 v2: 3x3 conv (512->64), K split 4-way across blocks, halo-staged pixels.
// [proven round 4 verbatim]
__global__ __launch_bounds__(256) void conv1_v2(
    const __bf16* __restrict__ AT, const __bf16* __restrict__ WT,
    float* __restrict__ P4)
{
    __shared__ __bf16 A9[9 * 64 * CSTR];
    __shared__ __bf16 HALO[240 * CSTR];
    const int kc = blockIdx.y, b = blockIdx.z, n0 = blockIdx.x * 128;
    const int t = threadIdx.x, lane = t & 63, wid = t >> 6;
    const int r = lane & 15, g = lane >> 4;

    int yj[2], xj[2];
#pragma unroll
    for (int j = 0; j < 2; ++j) {
        const int p = n0 + wid * 32 + j * 16 + r;
        yj[j] = p / IMG; xj[j] = p - yj[j] * IMG;
    }

    f32x4 acc[4][2] = {};

#pragma unroll 1
    for (int st = 0; st < 4; ++st) {
        const int cbase = kc * 128 + st * 32;
        if (t < 240) {
            const int nn = n0 - 56 + t;
            bf16x8 h0 = {}, h1 = {}, h2 = {}, h3 = {};
            if (nn >= 0 && nn < HW) {
                const bf16x8* sp = reinterpret_cast<const bf16x8*>(
                    AT + ((size_t)b * HW + nn) * 512 + cbase);
                h0 = sp[0]; h1 = sp[1]; h2 = sp[2]; h3 = sp[3];
            }
            bf16x8* dp = reinterpret_cast<bf16x8*>(HALO + t * CSTR);
            dp[0] = h0; dp[1] = h1; dp[2] = h2; dp[3] = h3;
        }
        {
            const int m = t >> 2, seg = t & 3;
#pragma unroll
            for (int tap = 0; tap < 9; ++tap)
                *reinterpret_cast<bf16x8*>(A9 + (tap * 64 + m) * CSTR + seg * 8) =
                    *reinterpret_cast<const bf16x8*>(WT + ((size_t)tap * 64 + m) * 512 + cbase + seg * 8);
        }
        __syncthreads();
#pragma unroll 1
        for (int tap = 0; tap < 9; ++tap) {
            const int dy = tap / 3 - 1;
            const int dx = tap - (tap / 3) * 3 - 1;
            bf16x8 bb[2];
#pragma unroll
            for (int j = 0; j < 2; ++j) {
                const bool valid = ((unsigned)(yj[j] + dy) < (unsigned)IMG) &&
                                   ((unsigned)(xj[j] + dx) < (unsigned)IMG);
                const int row = wid * 32 + j * 16 + r + 56 + dy * IMG + dx;
                bf16x8 v = {};
                if (valid) v = *reinterpret_cast<const bf16x8*>(HALO + row * CSTR + g * 8);
                bb[j] = v;
            }
            bf16x8 a[4];
#pragma unroll
            for (int i = 0; i < 4; ++i)
                a[i] = *reinterpret_cast<const bf16x8*>(A9 + (tap * 64 + i * 16 + r) * CSTR + g * 8);
#pragma unroll
            for (int i = 0; i < 4; ++i)
#pragma unroll
                for (int j = 0; j < 2; ++j)
                    acc[i][j] = __builtin_amdgcn_mfma_f32_16x16x32_bf16(a[i], bb[j], acc[i][j], 0, 0, 0);
        }
        __syncthreads();
    }
#pragma unroll
    for (int mi = 0; mi < 4; ++mi)
#pragma unroll
        for (int nj = 0; nj < 2; ++nj) {
            const int m = mi * 16 + g * 4;
            const int n = n0 + wid * 32 + nj * 16 + r;
#pragma unroll
            for (int q = 0; q < 4; ++q)
                P4[(((size_t)kc * BATCH + b) * CG + m + q) * HW + n] = acc[mi][nj][q];
        }
}

// ---------------------------------------------------------------------------
__global__ __launch_bounds__(256) void reduce_hb(
    const float* __restrict__ P4, const float* __restrict__ fb1,
    float* __restrict__ HB)
{
    const int idx = blockIdx.x * 256 + threadIdx.x;
    constexpr size_t STRIDE = (size_t)BATCH * CG * HW;
    const int m = (idx / HW) & 63;
    float s = P4[idx] + P4[idx + STRIDE] + P4[idx + 2 * STRIDE] + P4[idx + 3 * STRIDE];
    HB[idx] = fmaxf(s + fb1[m], 0.f);
}

// ---------------------------------------------------------------------------
__global__ __launch_bounds__(256) void gates_v2(
    const float* __restrict__ hbuf, const float* __restrict__ fw2,
    const float* __restrict__ fb2, float* __restrict__ g0buf)
{
    __shared__ float w2s[1152];
    __shared__ float par[2][4][64];
    const int t = threadIdx.x;
    for (int i = t; i < 1152; i += 256) w2s[i] = fw2[i];
    __syncthreads();
    const int px = t & 63, grp = t >> 6;
    const int idx = blockIdx.x * 64 + px;
    const int b = idx / HW;
    const int n = idx - b * HW;
    const int y = n / IMG, x = n - (n / IMG) * IMG;
    float c0 = 0.f, c1 = 0.f;
    const float* hb = hbuf + ((size_t)b * CG + grp * 16) * HW;
    for (int ci = 0; ci < 16; ++ci) {
        const float* hp = hb + (size_t)ci * HW;
        const float* w0 = &w2s[(grp * 16 + ci) * 9];
        const float* w1 = &w2s[576 + (grp * 16 + ci) * 9];
#pragma unroll
        for (int tap = 0; tap < 9; ++tap) {
            const int dy = tap / 3 - 1, dx = tap % 3 - 1;
            const int yy = y + dy, xx = x + dx;
            if (yy >= 0 && yy < IMG && xx >= 0 && xx < IMG) {
                const float hv = hp[yy * IMG + xx];
                c0 = fmaf(hv, w0[tap], c0);
                c1 = fmaf(hv, w1[tap], c1);
            }
        }
    }
    par[0][grp][px] = c0;
    par[1][grp][px] = c1;
    __syncthreads();
    if (t < 64) {
        const float s0 = par[0][0][t] + par[0][1][t] + par[0][2][t] + par[0][3][t] + fb2[0];
        const float s1 = par[1][0][t] + par[1][1][t] + par[1][2][t] + par[1][3][t] + fb2[1];
        g0buf[blockIdx.x * 64 + t] = 1.f / (1.f + __expf(s1 - s0));
    }
}

// ---------------------------------------------------------------------------
__global__ __launch_bounds__(256) void blend_kernel(
    const float* __restrict__ att1, const float* __restrict__ att2,
    const float* __restrict__ g0buf, float* __restrict__ out)
{
    const int i = blockIdx.x * 256 + threadIdx.x;
    const int r = i / 576;
    const int q = i - r * 576;
    const int b = r >> 8;
    const float4 a1 = reinterpret_cast<const float4*>(att1)[i];
    const float4 a2 = reinterpret_cast<const float4*>(att2)[i];
    const float4 g  = *reinterpret_cast<const float4*>(&g0buf[(size_t)b * HW + q * 4]);
    float4 o;
    o.x = g.x * a1.x + (1.f - g.x) * a2.x;
    o.y = g.y * a1.y + (1.f - g.y) * a2.y;
    o.z = g.z * a1.z + (1.f - g.z) * a2.z;
    o.w = g.w * a1.w + (1.f - g.w) * a2.w;
    reinterpret_cast<float4*>(out)[i] = o;
}

} // namespace

extern "C" void kernel_launch(void* const* d_in, const int* in_sizes, int n_in,
                              void* d_out, int out_size, void* d_ws, size_t ws_size,
                              hipStream_t stream)
{
    const float* x1  = (const float*)d_in[0];
    const float* x2  = (const float*)d_in[1];
    const float* wq1 = (const float*)d_in[2];
    const float* wk1 = (const float*)d_in[3];
    const float* wv1 = (const float*)d_in[4];
    const float* bv1 = (const float*)d_in[5];
    const float* g1  = (const float*)d_in[6];
    const float* wq2 = (const float*)d_in[7];
    const float* wk2 = (const float*)d_in[8];
    const float* wv2 = (const float*)d_in[9];
    const float* bv2 = (const float*)d_in[10];
    const float* g2  = (const float*)d_in[11];
    const float* fw1 = (const float*)d_in[12];
    const float* fb1 = (const float*)d_in[13];
    const float* fw2 = (const float*)d_in[14];
    const float* fb2 = (const float*)d_in[15];
    float* out = (float*)d_out;
    char*  wsb = (char*)d_ws;

    __bf16* QT1 = (__bf16*)(wsb + QT1_OFF);
    __bf16* KT1 = (__bf16*)(wsb + KT1_OFF);
    __bf16* VB1 = (__bf16*)(wsb + VB1_OFF);
    __bf16* QT2 = (__bf16*)(wsb + QT2_OFF);
    __bf16* KT2 = (__bf16*)(wsb + KT2_OFF);
    __bf16* VB2 = (__bf16*)(wsb + VB2_OFF);
    __bf16* AT  = (__bf16*)(wsb + AT_OFF);
    float*  A1  = (float*)(wsb + A1_OFF);
    float*  A2  = (float*)(wsb + A2_OFF);
    float*  HB  = (float*)(wsb + HB_OFF);
    float*  G0  = (float*)(wsb + G0_OFF);
    __bf16* WT  = (__bf16*)(wsb + WT_OFF);
    float*  P4  = (float*)(wsb + QT1_OFF);   // alias: free after attention

    (void)in_sizes; (void)n_in; (void)out_size; (void)ws_size;

    proj3_mfma<<<dim3(18, 2, 24), 256, 0, stream>>>(x1, x2, wq1, wk1, wv1, bv1, QT1, KT1, VB1);
    proj3_mfma<<<dim3(18, 2, 24), 256, 0, stream>>>(x2, x1, wq2, wk2, wv2, bv2, QT2, KT2, VB2);
    wprep<<<dim3(1152), 256, 0, stream>>>(fw1, WT);

    fused_pv3<<<dim3(18, 16), 512, 0, stream>>>(
        QT1, KT1, VB1, QT2, KT2, VB2, x1, x2, g1, g2, A1, A2, AT);

    conv1_v2<<<dim3(18, 4, 8), 256, 0, stream>>>(AT, WT, P4);
    reduce_hb<<<dim3(4608), 256, 0, stream>>>(P4, fb1, HB);
    gates_v2<<<dim3(288), 256, 0, stream>>>(HB, fw2, fb2, G0);
    blend_kernel<<<dim3(4608), 256, 0, stream>>>(A1, A2, G0, out);
}

// Round 7
// 541.492 us; speedup vs baseline: 5.0872x; 1.1667x over previous
//
#include <hip/hip_runtime.h>

namespace {

constexpr int BATCH = 8;
constexpr int CH    = 256;   // C
constexpr int HW    = 2304;  // 48*48
constexpr int IMG   = 48;
constexpr int CG    = 64;

typedef __bf16 bf16x8 __attribute__((ext_vector_type(8)));
typedef __bf16 bf16x4 __attribute__((ext_vector_type(4)));
typedef float  f32x4  __attribute__((ext_vector_type(4)));

constexpr int ROWB = 40;    // proj LDS row stride
constexpr int KSTRD = 136;  // flash K-tile stride (128 data + 8 pad, 272B = 16B-aligned)
constexpr int VSTRD = 68;   // flash V-tile stride (64 data + 4 pad)
constexpr int PSTRD = 130;  // flash P stride (128 data + 2 pad)
constexpr int CSTR = 40;    // conv LDS stride

// ---- ws layout (bytes) ----
constexpr size_t BF_SLAB = (size_t)BATCH * HW * CH * 2;      // 9,437,184
constexpr size_t QT1_OFF = 0;
constexpr size_t KT1_OFF = 1 * BF_SLAB;
constexpr size_t VB1_OFF = 2 * BF_SLAB;
constexpr size_t QT2_OFF = 3 * BF_SLAB;
constexpr size_t KT2_OFF = 4 * BF_SLAB;
constexpr size_t VB2_OFF = 5 * BF_SLAB;
constexpr size_t AT_OFF  = 6 * BF_SLAB;                      // bf16 [B][HW][512]
constexpr size_t A1_OFF  = AT_OFF + (size_t)BATCH * HW * 512 * 2;
constexpr size_t A2_OFF  = A1_OFF + (size_t)BATCH * CH * HW * 4;
constexpr size_t HB_OFF  = A2_OFF + (size_t)BATCH * CH * HW * 4;
constexpr size_t G0_OFF  = HB_OFF + (size_t)BATCH * CG * HW * 4;
constexpr size_t WT_OFF  = G0_OFF + (size_t)BATCH * HW * 4;
// end ~= 112 MB; P4 (conv partials) aliases QT1/KT1 slabs.

// stage 16 bf16 elems/thread from row-major src into [128][ROWB] LDS (256-thr)
__device__ __forceinline__ void stage_bf16(const __bf16* __restrict__ src, size_t srcStride,
                                           __bf16* dst, int t) {
    const int r = t & 127, s = t >> 7;
    const bf16x8* sp = reinterpret_cast<const bf16x8*>(src + (size_t)r * srcStride + s * 16);
    bf16x8* dp = reinterpret_cast<bf16x8*>(dst + r * ROWB + s * 16);
    dp[0] = sp[0];
    dp[1] = sp[1];
}

// stage 16 fp32 elems/thread (convert to bf16) into [128][ROWB] LDS (256-thr)
__device__ __forceinline__ void stage_f32(const float* __restrict__ src, size_t srcStride,
                                          __bf16* dst, int t) {
    const int r = t & 127, s = t >> 7;
    const float4* sp = reinterpret_cast<const float4*>(src + (size_t)r * srcStride + s * 16);
    float4 f0 = sp[0], f1 = sp[1], f2 = sp[2], f3 = sp[3];
    bf16x8 v0, v1;
    v0[0]=(__bf16)f0.x; v0[1]=(__bf16)f0.y; v0[2]=(__bf16)f0.z; v0[3]=(__bf16)f0.w;
    v0[4]=(__bf16)f1.x; v0[5]=(__bf16)f1.y; v0[6]=(__bf16)f1.z; v0[7]=(__bf16)f1.w;
    v1[0]=(__bf16)f2.x; v1[1]=(__bf16)f2.y; v1[2]=(__bf16)f2.z; v1[3]=(__bf16)f2.w;
    v1[4]=(__bf16)f3.x; v1[5]=(__bf16)f3.y; v1[6]=(__bf16)f3.z; v1[7]=(__bf16)f3.w;
    bf16x8* dp = reinterpret_cast<bf16x8*>(dst + r * ROWB + s * 16);
    dp[0] = v0;
    dp[1] = v1;
}

// 4-wave 128x128 MFMA step (proj) [proven r3]
__device__ __forceinline__ void frag_step(const __bf16* As, const __bf16* Bs,
                                          f32x4 (&acc)[4][4], int lane, int wm, int wn) {
    const int r = lane & 15, g = lane >> 4;
    bf16x8 a[4], b[4];
#pragma unroll
    for (int i = 0; i < 4; ++i) {
        a[i] = *reinterpret_cast<const bf16x8*>(As + (wm * 64 + i * 16 + r) * ROWB + g * 8);
        b[i] = *reinterpret_cast<const bf16x8*>(Bs + (wn * 64 + i * 16 + r) * ROWB + g * 8);
    }
#pragma unroll
    for (int i = 0; i < 4; ++i)
#pragma unroll
        for (int j = 0; j < 4; ++j)
            acc[i][j] = __builtin_amdgcn_mfma_f32_16x16x32_bf16(a[i], b[j], acc[i][j], 0, 0, 0);
}

// ---------------------------------------------------------------------------
// proj3: Q/K/V. Q,K TRANSPOSED bf16 [B][HW][256]; V [B][256][HW]. [proven r3-r5]
__global__ __launch_bounds__(256) void proj3_mfma(
    const float* __restrict__ Xsrc, const float* __restrict__ Xg,
    const float* __restrict__ wq, const float* __restrict__ wk,
    const float* __restrict__ wv, const float* __restrict__ bv,
    __bf16* __restrict__ QT, __bf16* __restrict__ KT, __bf16* __restrict__ VB)
{
    __shared__ __bf16 As[128 * ROWB];
    __shared__ __bf16 Bs[128 * ROWB];
    const int p = blockIdx.z >> 3;      // 0=Q 1=K 2=V
    const int b = blockIdx.z & 7;
    const float* W = (p == 0) ? wq : (p == 1) ? wk : wv;
    const float* X = (p == 0) ? Xsrc : Xg;
    const float* Xb = X + (size_t)b * CH * HW;

    const int t = threadIdx.x;
    const int lane = t & 63, wid = t >> 6;
    const int wm = wid >> 1, wn = wid & 1;
    const int m0 = blockIdx.y * 128, n0 = blockIdx.x * 128;

    f32x4 acc[4][4] = {};
    const int nB = t & 127, halfB = t >> 7;

    for (int k0 = 0; k0 < CH; k0 += 32) {
        stage_f32(W + (size_t)m0 * CH + k0, CH, As, t);
        float v[16];
#pragma unroll
        for (int kk = 0; kk < 16; ++kk)
            v[kk] = Xb[(size_t)(k0 + halfB * 16 + kk) * HW + n0 + nB];
        bf16x8 p0, p1;
#pragma unroll
        for (int kk = 0; kk < 8; ++kk) { p0[kk] = (__bf16)v[kk]; p1[kk] = (__bf16)v[kk + 8]; }
        bf16x8* dp = reinterpret_cast<bf16x8*>(Bs + nB * ROWB + halfB * 16);
        dp[0] = p0; dp[1] = p1;
        __syncthreads();
        frag_step(As, Bs, acc, lane, wm, wn);
        __syncthreads();
    }

    const int g = lane >> 4, r = lane & 15;
    if (p < 2) {
        __bf16* T = (p == 0) ? QT : KT;
#pragma unroll
        for (int mi = 0; mi < 4; ++mi)
#pragma unroll
            for (int nj = 0; nj < 4; ++nj) {
                const int mb = m0 + wm * 64 + mi * 16 + g * 4;
                const int n  = n0 + wn * 64 + nj * 16 + r;
                bf16x4 pk;
#pragma unroll
                for (int q = 0; q < 4; ++q) pk[q] = (__bf16)acc[mi][nj][q];
                *reinterpret_cast<bf16x4*>(T + ((size_t)b * HW + n) * CH + mb) = pk;
            }
    } else {
#pragma unroll
        for (int mi = 0; mi < 4; ++mi)
#pragma unroll
            for (int nj = 0; nj < 4; ++nj) {
                const int mb = m0 + wm * 64 + mi * 16 + g * 4;
                const int n  = n0 + wn * 64 + nj * 16 + r;
#pragma unroll
                for (int q = 0; q < 4; ++q)
                    VB[((size_t)b * CH + mb + q) * HW + n] = (__bf16)(acc[mi][nj][q] + bv[mb + q]);
            }
    }
}

// ---------------------------------------------------------------------------
// fused_flash: single-sweep flash attention. 256 thr (4 waves), QBLK=64 rows.
// Wave w owns q-rows [w*16,w*16+16) (stats wave-local, Q in regs) and c-chunk
// [w*64,w*64+64) for PV (all n). grid 576 = 36 n-tiles x 16 z, XCD-swizzled.
__global__ __launch_bounds__(256, 3) void fused_flash(
    const __bf16* __restrict__ QT1, const __bf16* __restrict__ KT1, const __bf16* __restrict__ VB1,
    const __bf16* __restrict__ QT2, const __bf16* __restrict__ KT2, const __bf16* __restrict__ VB2,
    const float* __restrict__ x1, const float* __restrict__ x2,
    const float* __restrict__ g1, const float* __restrict__ g2,
    float* __restrict__ A1, float* __restrict__ A2, __bf16* __restrict__ AT)
{
    __shared__ __bf16 KV[17408];           // Ks[128][136] (17408) ∪ Vs[256][68] (17408)
    __shared__ __bf16 P_lds[64 * PSTRD];   // 16.6 KB
    __shared__ float  sc_lds[64];          // per-row scale / final 1/sum
    __bf16* Ks = KV;
    __bf16* Vs = KV;

    // XCD swizzle: 576 = 8 * 72; contiguous 72-block chunk (2 z) per XCD
    const int bid  = blockIdx.x;
    const int work = (bid & 7) * 72 + (bid >> 3);
    const int z = work / 36, ntile = work - z * 36;

    const int att = z >> 3, b = z & 7;
    const __bf16* QT = att ? QT2 : QT1;
    const __bf16* KT = att ? KT2 : KT1;
    const __bf16* VB = att ? VB2 : VB1;
    const float* src = att ? x2 : x1;
    const float* gmp = att ? g2 : g1;
    float* A         = att ? A2 : A1;
    const int aoff   = att ? CH : 0;

    const int t = threadIdx.x, lane = t & 63, w = t >> 6;
    const int r = lane & 15, g = lane >> 4;
    const int n0 = ntile * 64;

    // Q rows in registers: row n0 + w*16 + r, full K=256
    bf16x8 qf[8];
    {
        const __bf16* qrow = QT + ((size_t)b * HW + n0 + w * 16 + r) * CH;
#pragma unroll
        for (int kc = 0; kc < 8; ++kc)
            qf[kc] = *reinterpret_cast<const bf16x8*>(qrow + kc * 32 + g * 8);
    }

    float m_run[4] = {-3.0e38f, -3.0e38f, -3.0e38f, -3.0e38f};
    float s_run[4] = {0.f, 0.f, 0.f, 0.f};
    f32x4 accO[4][4] = {};

    for (int m0 = 0; m0 < HW; m0 += 128) {
        // ---- S phase: accS[j] = this wave's 16 q-rows x 128 m-cols
        f32x4 accS[8] = {};
#pragma unroll 1
        for (int k0 = 0; k0 < CH; k0 += 128) {
            {   // stage Ks: 128 m-rows x 128 k; thread t owns row t>>1, 64-col half
                const int kr = t >> 1, kcol = (t & 1) * 64;
                const bf16x8* sp = reinterpret_cast<const bf16x8*>(
                    KT + ((size_t)b * HW + m0 + kr) * CH + k0 + kcol);
                bf16x8* dp = reinterpret_cast<bf16x8*>(Ks + kr * KSTRD + kcol);
#pragma unroll
                for (int u = 0; u < 8; ++u) dp[u] = sp[u];
            }
            __syncthreads();
            __builtin_amdgcn_s_setprio(1);
#pragma unroll
            for (int kk = 0; kk < 4; ++kk) {
                const bf16x8 qv = qf[(k0 >> 5) + kk];
#pragma unroll
                for (int j = 0; j < 8; ++j) {
                    const bf16x8 bb = *reinterpret_cast<const bf16x8*>(
                        Ks + (j * 16 + r) * KSTRD + kk * 32 + g * 8);
                    accS[j] = __builtin_amdgcn_mfma_f32_16x16x32_bf16(qv, bb, accS[j], 0, 0, 0);
                }
            }
            __builtin_amdgcn_s_setprio(0);
            __syncthreads();
        }
        // ---- wave-local online stats + P write
#pragma unroll
        for (int q = 0; q < 4; ++q) {
            float tmax = accS[0][q];
#pragma unroll
            for (int j = 1; j < 8; ++j) tmax = fmaxf(tmax, accS[j][q]);
            tmax = fmaxf(tmax, __shfl_xor(tmax, 1));
            tmax = fmaxf(tmax, __shfl_xor(tmax, 2));
            tmax = fmaxf(tmax, __shfl_xor(tmax, 4));
            tmax = fmaxf(tmax, __shfl_xor(tmax, 8));
            const float nm = fmaxf(m_run[q], tmax);
            float pe[8];
            float ts = 0.f;
#pragma unroll
            for (int j = 0; j < 8; ++j) { pe[j] = __expf(accS[j][q] - nm); ts += pe[j]; }
#pragma unroll
            for (int j = 0; j < 8; ++j)
                P_lds[(w * 16 + g * 4 + q) * PSTRD + j * 16 + r] = (__bf16)pe[j];
            ts += __shfl_xor(ts, 1);
            ts += __shfl_xor(ts, 2);
            ts += __shfl_xor(ts, 4);
            ts += __shfl_xor(ts, 8);
            const float scale = __expf(m_run[q] - nm);
            s_run[q] = s_run[q] * scale + ts;
            m_run[q] = nm;
            if (r == 0) sc_lds[w * 16 + g * 4 + q] = scale;
        }
        __syncthreads();
        // ---- rescale accO by per-n scale
        {
            float scj[4];
#pragma unroll
            for (int j = 0; j < 4; ++j) scj[j] = sc_lds[j * 16 + r];
#pragma unroll
            for (int i = 0; i < 4; ++i)
#pragma unroll
                for (int j = 0; j < 4; ++j)
#pragma unroll
                    for (int q = 0; q < 4; ++q) accO[i][j][q] *= scj[j];
        }
        // ---- PV: O[c][n] += V[c][m-chunk] * P[n][m-chunk]
#pragma unroll 1
        for (int vc = 0; vc < 2; ++vc) {
            {   // stage Vs: 256 c-rows x 64 m; thread t owns full row t
                const bf16x8* sv = reinterpret_cast<const bf16x8*>(
                    VB + ((size_t)b * CH + t) * HW + m0 + vc * 64);
                bf16x8* dv = reinterpret_cast<bf16x8*>(Vs + t * VSTRD);
#pragma unroll
                for (int u = 0; u < 8; ++u) dv[u] = sv[u];
            }
            __syncthreads();
            __builtin_amdgcn_s_setprio(1);
#pragma unroll
            for (int kk = 0; kk < 2; ++kk) {
                bf16x8 av[4], bp[4];
#pragma unroll
                for (int i = 0; i < 4; ++i)
                    av[i] = *reinterpret_cast<const bf16x8*>(
                        Vs + (w * 64 + i * 16 + r) * VSTRD + kk * 32 + g * 8);
#pragma unroll
                for (int j = 0; j < 4; ++j)
                    bp[j] = *reinterpret_cast<const bf16x8*>(
                        P_lds + (j * 16 + r) * PSTRD + vc * 64 + kk * 32 + g * 8);
#pragma unroll
                for (int i = 0; i < 4; ++i)
#pragma unroll
                    for (int j = 0; j < 4; ++j)
                        accO[i][j] = __builtin_amdgcn_mfma_f32_16x16x32_bf16(av[i], bp[j], accO[i][j], 0, 0, 0);
            }
            __builtin_amdgcn_s_setprio(0);
            __syncthreads();
        }
    }

    // ---- epilogue: out = gamma * (1/s) * accO + src
    if (r == 0) {
#pragma unroll
        for (int q = 0; q < 4; ++q) sc_lds[w * 16 + g * 4 + q] = 1.f / s_run[q];
    }
    __syncthreads();
    float IS_l[4];
#pragma unroll
    for (int j = 0; j < 4; ++j) IS_l[j] = sc_lds[j * 16 + r];
    const float gm = gmp[0];
#pragma unroll
    for (int i = 0; i < 4; ++i)
#pragma unroll
        for (int j = 0; j < 4; ++j) {
            const int cb = w * 64 + i * 16 + g * 4;
            const int n  = n0 + j * 16 + r;
            const float sc = gm * IS_l[j];
            float vals[4];
#pragma unroll
            for (int q = 0; q < 4; ++q) {
                const size_t idx = ((size_t)b * CH + cb + q) * HW + n;
                vals[q] = sc * accO[i][j][q] + src[idx];
                A[idx] = vals[q];
            }
            bf16x4 pk;
#pragma unroll
            for (int q = 0; q < 4; ++q) pk[q] = (__bf16)vals[q];
            *reinterpret_cast<bf16x4*>(AT + ((size_t)b * HW + n) * 512 + aoff + cb) = pk;
        }
}

// ---------------------------------------------------------------------------
// wprep: fw1 [64][512*9] fp32 -> WT bf16 [tap][m][512]
__global__ __launch_bounds__(256) void wprep(const float* __restrict__ fw1,
                                             __bf16* __restrict__ WT)
{
    const int i = blockIdx.x * 256 + threadIdx.x;   // 9*64*512 exact
    const int tap = i >> 15;
    const int rem = i & 32767;
    const int m = rem >> 9, c = rem & 511;
    WT[i] = (__bf16)fw1[(size_t)m * 4608 + c * 9 + tap];
}

// ---------------------------------------------------------------------------
// conv1 v2 [proven r4/r5 verbatim]
__global__ __launch_bounds__(256) void conv1_v2(
    const __bf16* __restrict__ AT, const __bf16* __restrict__ WT,
    float* __restrict__ P4)
{
    __shared__ __bf16 A9[9 * 64 * CSTR];
    __shared__ __bf16 HALO[240 * CSTR];
    const int kc = blockIdx.y, b = blockIdx.z, n0 = blockIdx.x * 128;
    const int t = threadIdx.x, lane = t & 63, wid = t >> 6;
    const int r = lane & 15, g = lane >> 4;

    int yj[2], xj[2];
#pragma unroll
    for (int j = 0; j < 2; ++j) {
        const int p = n0 + wid * 32 + j * 16 + r;
        yj[j] = p / IMG; xj[j] = p - yj[j] * IMG;
    }

    f32x4 acc[4][2] = {};

#pragma unroll 1
    for (int st = 0; st < 4; ++st) {
        const int cbase = kc * 128 + st * 32;
        if (t < 240) {
            const int nn = n0 - 56 + t;
            bf16x8 h0 = {}, h1 = {}, h2 = {}, h3 = {};
            if (nn >= 0 && nn < HW) {
                const bf16x8* sp = reinterpret_cast<const bf16x8*>(
                    AT + ((size_t)b * HW + nn) * 512 + cbase);
                h0 = sp[0]; h1 = sp[1]; h2 = sp[2]; h3 = sp[3];
            }
            bf16x8* dp = reinterpret_cast<bf16x8*>(HALO + t * CSTR);
            dp[0] = h0; dp[1] = h1; dp[2] = h2; dp[3] = h3;
        }
        {
            const int m = t >> 2, seg = t & 3;
#pragma unroll
            for (int tap = 0; tap < 9; ++tap)
                *reinterpret_cast<bf16x8*>(A9 + (tap * 64 + m) * CSTR + seg * 8) =
                    *reinterpret_cast<const bf16x8*>(WT + ((size_t)tap * 64 + m) * 512 + cbase + seg * 8);
        }
        __syncthreads();
#pragma unroll 1
        for (int tap = 0; tap < 9; ++tap) {
            const int dy = tap / 3 - 1;
            const int dx = tap - (tap / 3) * 3 - 1;
            bf16x8 bb[2];
#pragma unroll
            for (int j = 0; j < 2; ++j) {
                const bool valid = ((unsigned)(yj[j] + dy) < (unsigned)IMG) &&
                                   ((unsigned)(xj[j] + dx) < (unsigned)IMG);
                const int row = wid * 32 + j * 16 + r + 56 + dy * IMG + dx;
                bf16x8 v = {};
                if (valid) v = *reinterpret_cast<const bf16x8*>(HALO + row * CSTR + g * 8);
                bb[j] = v;
            }
            bf16x8 a[4];
#pragma unroll
            for (int i = 0; i < 4; ++i)
                a[i] = *reinterpret_cast<const bf16x8*>(A9 + (tap * 64 + i * 16 + r) * CSTR + g * 8);
#pragma unroll
            for (int i = 0; i < 4; ++i)
#pragma unroll
                for (int j = 0; j < 2; ++j)
                    acc[i][j] = __builtin_amdgcn_mfma_f32_16x16x32_bf16(a[i], bb[j], acc[i][j], 0, 0, 0);
        }
        __syncthreads();
    }
#pragma unroll
    for (int mi = 0; mi < 4; ++mi)
#pragma unroll
        for (int nj = 0; nj < 2; ++nj) {
            const int m = mi * 16 + g * 4;
            const int n = n0 + wid * 32 + nj * 16 + r;
#pragma unroll
            for (int q = 0; q < 4; ++q)
                P4[(((size_t)kc * BATCH + b) * CG + m + q) * HW + n] = acc[mi][nj][q];
        }
}

// ---------------------------------------------------------------------------
__global__ __launch_bounds__(256) void reduce_hb(
    const float* __restrict__ P4, const float* __restrict__ fb1,
    float* __restrict__ HB)
{
    const int idx = blockIdx.x * 256 + threadIdx.x;
    constexpr size_t STRIDE = (size_t)BATCH * CG * HW;
    const int m = (idx / HW) & 63;
    float s = P4[idx] + P4[idx + STRIDE] + P4[idx + 2 * STRIDE] + P4[idx + 3 * STRIDE];
    HB[idx] = fmaxf(s + fb1[m], 0.f);
}

// ---------------------------------------------------------------------------
__global__ __launch_bounds__(256) void gates_v2(
    const float* __restrict__ hbuf, const float* __restrict__ fw2,
    const float* __restrict__ fb2, float* __restrict__ g0buf)
{
    __shared__ float w2s[1152];
    __shared__ float par[2][4][64];
    const int t = threadIdx.x;
    for (int i = t; i < 1152; i += 256) w2s[i] = fw2[i];
    __syncthreads();
    const int px = t & 63, grp = t >> 6;
    const int idx = blockIdx.x * 64 + px;
    const int b = idx / HW;
    const int n = idx - b * HW;
    const int y = n / IMG, x = n - (n / IMG) * IMG;
    float c0 = 0.f, c1 = 0.f;
    const float* hb = hbuf + ((size_t)b * CG + grp * 16) * HW;
    for (int ci = 0; ci < 16; ++ci) {
        const float* hp = hb + (size_t)ci * HW;
        const float* w0 = &w2s[(grp * 16 + ci) * 9];
        const float* w1 = &w2s[576 + (grp * 16 + ci) * 9];
#pragma unroll
        for (int tap = 0; tap < 9; ++tap) {
            const int dy = tap / 3 - 1, dx = tap % 3 - 1;
            const int yy = y + dy, xx = x + dx;
            if (yy >= 0 && yy < IMG && xx >= 0 && xx < IMG) {
                const float hv = hp[yy * IMG + xx];
                c0 = fmaf(hv, w0[tap], c0);
                c1 = fmaf(hv, w1[tap], c1);
            }
        }
    }
    par[0][grp][px] = c0;
    par[1][grp][px] = c1;
    __syncthreads();
    if (t < 64) {
        const float s0 = par[0][0][t] + par[0][1][t] + par[0][2][t] + par[0][3][t] + fb2[0];
        const float s1 = par[1][0][t] + par[1][1][t] + par[1][2][t] + par[1][3][t] + fb2[1];
        g0buf[blockIdx.x * 64 + t] = 1.f / (1.f + __expf(s1 - s0));
    }
}

// ---------------------------------------------------------------------------
__global__ __launch_bounds__(256) void blend_kernel(
    const float* __restrict__ att1, const float* __restrict__ att2,
    const float* __restrict__ g0buf, float* __restrict__ out)
{
    const int i = blockIdx.x * 256 + threadIdx.x;
    const int r = i / 576;
    const int q = i - r * 576;
    const int b = r >> 8;
    const float4 a1 = reinterpret_cast<const float4*>(att1)[i];
    const float4 a2 = reinterpret_cast<const float4*>(att2)[i];
    const float4 g  = *reinterpret_cast<const float4*>(&g0buf[(size_t)b * HW + q * 4]);
    float4 o;
    o.x = g.x * a1.x + (1.f - g.x) * a2.x;
    o.y = g.y * a1.y + (1.f - g.y) * a2.y;
    o.z = g.z * a1.z + (1.f - g.z) * a2.z;
    o.w = g.w * a1.w + (1.f - g.w) * a2.w;
    reinterpret_cast<float4*>(out)[i] = o;
}

} // namespace

extern "C" void kernel_launch(void* const* d_in, const int* in_sizes, int n_in,
                              void* d_out, int out_size, void* d_ws, size_t ws_size,
                              hipStream_t stream)
{
    const float* x1  = (const float*)d_in[0];
    const float* x2  = (const float*)d_in[1];
    const float* wq1 = (const float*)d_in[2];
    const float* wk1 = (const float*)d_in[3];
    const float* wv1 = (const float*)d_in[4];
    const float* bv1 = (const float*)d_in[5];
    const float* g1  = (const float*)d_in[6];
    const float* wq2 = (const float*)d_in[7];
    const float* wk2 = (const float*)d_in[8];
    const float* wv2 = (const float*)d_in[9];
    const float* bv2 = (const float*)d_in[10];
    const float* g2  = (const float*)d_in[11];
    const float* fw1 = (const float*)d_in[12];
    const float* fb1 = (const float*)d_in[13];
    const float* fw2 = (const float*)d_in[14];
    const float* fb2 = (const float*)d_in[15];
    float* out = (float*)d_out;
    char*  wsb = (char*)d_ws;

    __bf16* QT1 = (__bf16*)(wsb + QT1_OFF);
    __bf16* KT1 = (__bf16*)(wsb + KT1_OFF);
    __bf16* VB1 = (__bf16*)(wsb + VB1_OFF);
    __bf16* QT2 = (__bf16*)(wsb + QT2_OFF);
    __bf16* KT2 = (__bf16*)(wsb + KT2_OFF);
    __bf16* VB2 = (__bf16*)(wsb + VB2_OFF);
    __bf16* AT  = (__bf16*)(wsb + AT_OFF);
    float*  A1  = (float*)(wsb + A1_OFF);
    float*  A2  = (float*)(wsb + A2_OFF);
    float*  HB  = (float*)(wsb + HB_OFF);
    float*  G0  = (float*)(wsb + G0_OFF);
    __bf16* WT  = (__bf16*)(wsb + WT_OFF);
    float*  P4  = (float*)(wsb + QT1_OFF);   // alias: free after attention

    (void)in_sizes; (void)n_in; (void)out_size; (void)ws_size;

    proj3_mfma<<<dim3(18, 2, 24), 256, 0, stream>>>(x1, x2, wq1, wk1, wv1, bv1, QT1, KT1, VB1);
    proj3_mfma<<<dim3(18, 2, 24), 256, 0, stream>>>(x2, x1, wq2, wk2, wv2, bv2, QT2, KT2, VB2);
    wprep<<<dim3(1152), 256, 0, stream>>>(fw1, WT);

    fused_flash<<<dim3(576), 256, 0, stream>>>(
        QT1, KT1, VB1, QT2, KT2, VB2, x1, x2, g1, g2, A1, A2, AT);

    conv1_v2<<<dim3(18, 4, 8), 256, 0, stream>>>(AT, WT, P4);
    reduce_hb<<<dim3(4608), 256, 0, stream>>>(P4, fb1, HB);
    gates_v2<<<dim3(288), 256, 0, stream>>>(HB, fw2, fb2, G0);
    blend_kernel<<<dim3(4608), 256, 0, stream>>>(A1, A2, G0, out);
}

// Round 8
// 478.649 us; speedup vs baseline: 5.7551x; 1.1313x over previous
//
#include <hip/hip_runtime.h>

namespace {

constexpr int BATCH = 8;
constexpr int CH    = 256;   // C
constexpr int HW    = 2304;  // 48*48
constexpr int IMG   = 48;
constexpr int CG    = 64;

typedef __bf16 bf16x8 __attribute__((ext_vector_type(8)));
typedef __bf16 bf16x4 __attribute__((ext_vector_type(4)));
typedef float  f32x4  __attribute__((ext_vector_type(4)));

constexpr int ROWB = 40;    // proj LDS row stride
constexpr int KSTRD = 136;  // flash K-tile stride (128 data + 8 pad, 272B, 16B-aligned)
constexpr int VSTRD = 68;   // flash V-tile stride (64 data + 4 pad)
constexpr int PSTRD = 132;  // flash P stride (128 data + 4 pad, 264B, 8B-aligned rows)
constexpr int CSTR = 40;    // conv LDS stride

// ---- ws layout (bytes) ----
constexpr size_t BF_SLAB = (size_t)BATCH * HW * CH * 2;      // 9,437,184
constexpr size_t QT1_OFF = 0;
constexpr size_t KT1_OFF = 1 * BF_SLAB;
constexpr size_t VB1_OFF = 2 * BF_SLAB;
constexpr size_t QT2_OFF = 3 * BF_SLAB;
constexpr size_t KT2_OFF = 4 * BF_SLAB;
constexpr size_t VB2_OFF = 5 * BF_SLAB;
constexpr size_t AT_OFF  = 6 * BF_SLAB;                      // bf16 [B][HW][512]
constexpr size_t A1_OFF  = AT_OFF + (size_t)BATCH * HW * 512 * 2;
constexpr size_t A2_OFF  = A1_OFF + (size_t)BATCH * CH * HW * 4;
constexpr size_t HB_OFF  = A2_OFF + (size_t)BATCH * CH * HW * 4;
constexpr size_t G0_OFF  = HB_OFF + (size_t)BATCH * CG * HW * 4;
constexpr size_t WT_OFF  = G0_OFF + (size_t)BATCH * HW * 4;
// end ~= 112 MB; P4 (conv partials) aliases QT1/KT1 slabs.

// stage 16 bf16 elems/thread from row-major src into [128][ROWB] LDS (256-thr)
__device__ __forceinline__ void stage_bf16(const __bf16* __restrict__ src, size_t srcStride,
                                           __bf16* dst, int t) {
    const int r = t & 127, s = t >> 7;
    const bf16x8* sp = reinterpret_cast<const bf16x8*>(src + (size_t)r * srcStride + s * 16);
    bf16x8* dp = reinterpret_cast<bf16x8*>(dst + r * ROWB + s * 16);
    dp[0] = sp[0];
    dp[1] = sp[1];
}

// stage 16 fp32 elems/thread (convert to bf16) into [128][ROWB] LDS (256-thr)
__device__ __forceinline__ void stage_f32(const float* __restrict__ src, size_t srcStride,
                                          __bf16* dst, int t) {
    const int r = t & 127, s = t >> 7;
    const float4* sp = reinterpret_cast<const float4*>(src + (size_t)r * srcStride + s * 16);
    float4 f0 = sp[0], f1 = sp[1], f2 = sp[2], f3 = sp[3];
    bf16x8 v0, v1;
    v0[0]=(__bf16)f0.x; v0[1]=(__bf16)f0.y; v0[2]=(__bf16)f0.z; v0[3]=(__bf16)f0.w;
    v0[4]=(__bf16)f1.x; v0[5]=(__bf16)f1.y; v0[6]=(__bf16)f1.z; v0[7]=(__bf16)f1.w;
    v1[0]=(__bf16)f2.x; v1[1]=(__bf16)f2.y; v1[2]=(__bf16)f2.z; v1[3]=(__bf16)f2.w;
    v1[4]=(__bf16)f3.x; v1[5]=(__bf16)f3.y; v1[6]=(__bf16)f3.z; v1[7]=(__bf16)f3.w;
    bf16x8* dp = reinterpret_cast<bf16x8*>(dst + r * ROWB + s * 16);
    dp[0] = v0;
    dp[1] = v1;
}

// 4-wave 128x128 MFMA step (proj) [proven r3]
__device__ __forceinline__ void frag_step(const __bf16* As, const __bf16* Bs,
                                          f32x4 (&acc)[4][4], int lane, int wm, int wn) {
    const int r = lane & 15, g = lane >> 4;
    bf16x8 a[4], b[4];
#pragma unroll
    for (int i = 0; i < 4; ++i) {
        a[i] = *reinterpret_cast<const bf16x8*>(As + (wm * 64 + i * 16 + r) * ROWB + g * 8);
        b[i] = *reinterpret_cast<const bf16x8*>(Bs + (wn * 64 + i * 16 + r) * ROWB + g * 8);
    }
#pragma unroll
    for (int i = 0; i < 4; ++i)
#pragma unroll
        for (int j = 0; j < 4; ++j)
            acc[i][j] = __builtin_amdgcn_mfma_f32_16x16x32_bf16(a[i], b[j], acc[i][j], 0, 0, 0);
}

// ---------------------------------------------------------------------------
// proj3: Q/K/V. Q,K TRANSPOSED bf16 [B][HW][256]; V [B][256][HW]. [proven r3-r7]
__global__ __launch_bounds__(256) void proj3_mfma(
    const float* __restrict__ Xsrc, const float* __restrict__ Xg,
    const float* __restrict__ wq, const float* __restrict__ wk,
    const float* __restrict__ wv, const float* __restrict__ bv,
    __bf16* __restrict__ QT, __bf16* __restrict__ KT, __bf16* __restrict__ VB)
{
    __shared__ __bf16 As[128 * ROWB];
    __shared__ __bf16 Bs[128 * ROWB];
    const int p = blockIdx.z >> 3;      // 0=Q 1=K 2=V
    const int b = blockIdx.z & 7;
    const float* W = (p == 0) ? wq : (p == 1) ? wk : wv;
    const float* X = (p == 0) ? Xsrc : Xg;
    const float* Xb = X + (size_t)b * CH * HW;

    const int t = threadIdx.x;
    const int lane = t & 63, wid = t >> 6;
    const int wm = wid >> 1, wn = wid & 1;
    const int m0 = blockIdx.y * 128, n0 = blockIdx.x * 128;

    f32x4 acc[4][4] = {};
    const int nB = t & 127, halfB = t >> 7;

    for (int k0 = 0; k0 < CH; k0 += 32) {
        stage_f32(W + (size_t)m0 * CH + k0, CH, As, t);
        float v[16];
#pragma unroll
        for (int kk = 0; kk < 16; ++kk)
            v[kk] = Xb[(size_t)(k0 + halfB * 16 + kk) * HW + n0 + nB];
        bf16x8 p0, p1;
#pragma unroll
        for (int kk = 0; kk < 8; ++kk) { p0[kk] = (__bf16)v[kk]; p1[kk] = (__bf16)v[kk + 8]; }
        bf16x8* dp = reinterpret_cast<bf16x8*>(Bs + nB * ROWB + halfB * 16);
        dp[0] = p0; dp[1] = p1;
        __syncthreads();
        frag_step(As, Bs, acc, lane, wm, wn);
        __syncthreads();
    }

    const int g = lane >> 4, r = lane & 15;
    if (p < 2) {
        __bf16* T = (p == 0) ? QT : KT;
#pragma unroll
        for (int mi = 0; mi < 4; ++mi)
#pragma unroll
            for (int nj = 0; nj < 4; ++nj) {
                const int mb = m0 + wm * 64 + mi * 16 + g * 4;
                const int n  = n0 + wn * 64 + nj * 16 + r;
                bf16x4 pk;
#pragma unroll
                for (int q = 0; q < 4; ++q) pk[q] = (__bf16)acc[mi][nj][q];
                *reinterpret_cast<bf16x4*>(T + ((size_t)b * HW + n) * CH + mb) = pk;
            }
    } else {
#pragma unroll
        for (int mi = 0; mi < 4; ++mi)
#pragma unroll
            for (int nj = 0; nj < 4; ++nj) {
                const int mb = m0 + wm * 64 + mi * 16 + g * 4;
                const int n  = n0 + wn * 64 + nj * 16 + r;
#pragma unroll
                for (int q = 0; q < 4; ++q)
                    VB[((size_t)b * CH + mb + q) * HW + n] = (__bf16)(acc[mi][nj][q] + bv[mb + q]);
            }
    }
}

// ---------------------------------------------------------------------------
// fused_flash v2: single-sweep flash attention, swapped-operand S (in-lane
// softmax rows). 256 thr (4 waves), QBLK=64. Lane (r,g) of wave w owns q-row
// n0+w*16+r end-to-end; wave w owns c-chunk w*64 in PV.
// grid 576 = 36 n-tiles x 16 z, XCD-swizzled.
__global__ __launch_bounds__(256, 3) void fused_flash(
    const __bf16* __restrict__ QT1, const __bf16* __restrict__ KT1, const __bf16* __restrict__ VB1,
    const __bf16* __restrict__ QT2, const __bf16* __restrict__ KT2, const __bf16* __restrict__ VB2,
    const float* __restrict__ x1, const float* __restrict__ x2,
    const float* __restrict__ g1, const float* __restrict__ g2,
    float* __restrict__ A1, float* __restrict__ A2, __bf16* __restrict__ AT)
{
    __shared__ __bf16 KV[17408];           // Ks[128][136] (34816B) ∪ Vs[256][68] (34816B)
    __shared__ __bf16 P_lds[64 * PSTRD];   // 16.9 KB, layout [q-row 64][m 128]
    __shared__ float  sc_lds[64];          // per-row scale / final 1/sum
    __bf16* Ks = KV;
    __bf16* Vs = KV;

    // XCD swizzle: 576 = 8 * 72; contiguous 72-block chunk (2 z) per XCD
    const int bid  = blockIdx.x;
    const int work = (bid & 7) * 72 + (bid >> 3);
    const int z = work / 36, ntile = work - z * 36;

    const int att = z >> 3, b = z & 7;
    const __bf16* QT = att ? QT2 : QT1;
    const __bf16* KT = att ? KT2 : KT1;
    const __bf16* VB = att ? VB2 : VB1;
    const float* src = att ? x2 : x1;
    const float* gmp = att ? g2 : g1;
    float* A         = att ? A2 : A1;
    const int aoff   = att ? CH : 0;

    const int t = threadIdx.x, lane = t & 63, w = t >> 6;
    const int r = lane & 15, g = lane >> 4;
    const int n0 = ntile * 64;

    // Q row in registers: q-row n0 + w*16 + r, full K=256 (compile-time indexed)
    bf16x8 qf[8];
    {
        const __bf16* qrow = QT + ((size_t)b * HW + n0 + w * 16 + r) * CH;
#pragma unroll
        for (int kc = 0; kc < 8; ++kc)
            qf[kc] = *reinterpret_cast<const bf16x8*>(qrow + kc * 32 + g * 8);
    }

    float m_run = -3.0e38f;
    float s_run = 0.f;
    f32x4 accO[4][4] = {};

    for (int m0 = 0; m0 < HW; m0 += 128) {
        // ---- S phase (SWAPPED): accS[j] = S^T[m-group j][q-col r]
        f32x4 accS[8] = {};
#pragma unroll
        for (int kh = 0; kh < 2; ++kh) {      // FULL unroll: qf indices compile-time
            {   // stage Ks: 128 m-rows x 128 k
                const int kr = t >> 1, kcol = (t & 1) * 64;
                const bf16x8* sp = reinterpret_cast<const bf16x8*>(
                    KT + ((size_t)b * HW + m0 + kr) * CH + kh * 128 + kcol);
                bf16x8* dp = reinterpret_cast<bf16x8*>(Ks + kr * KSTRD + kcol);
#pragma unroll
                for (int u = 0; u < 8; ++u) dp[u] = sp[u];
            }
            __syncthreads();
            __builtin_amdgcn_s_setprio(1);
#pragma unroll
            for (int kk = 0; kk < 4; ++kk) {
                const bf16x8 qv = qf[kh * 4 + kk];
#pragma unroll
                for (int j = 0; j < 8; ++j) {
                    const bf16x8 kf = *reinterpret_cast<const bf16x8*>(
                        Ks + (j * 16 + r) * KSTRD + kk * 32 + g * 8);
                    accS[j] = __builtin_amdgcn_mfma_f32_16x16x32_bf16(kf, qv, accS[j], 0, 0, 0);
                }
            }
            __builtin_amdgcn_s_setprio(0);
            __syncthreads();
        }
        // ---- in-lane online softmax: lane holds 32 S-values of ONE q-row
        {
            float tmax = accS[0][0];
#pragma unroll
            for (int j = 0; j < 8; ++j)
#pragma unroll
                for (int q = 0; q < 4; ++q) tmax = fmaxf(tmax, accS[j][q]);
            tmax = fmaxf(tmax, __shfl_xor(tmax, 16));
            tmax = fmaxf(tmax, __shfl_xor(tmax, 32));
            const float nm = fmaxf(m_run, tmax);
            float ts = 0.f;
#pragma unroll
            for (int j = 0; j < 8; ++j) {
                const float pe0 = __expf(accS[j][0] - nm);
                const float pe1 = __expf(accS[j][1] - nm);
                const float pe2 = __expf(accS[j][2] - nm);
                const float pe3 = __expf(accS[j][3] - nm);
                ts += (pe0 + pe1) + (pe2 + pe3);
                bf16x4 pk;
                pk[0] = (__bf16)pe0; pk[1] = (__bf16)pe1;
                pk[2] = (__bf16)pe2; pk[3] = (__bf16)pe3;
                *reinterpret_cast<bf16x4*>(
                    P_lds + (w * 16 + r) * PSTRD + j * 16 + g * 4) = pk;
            }
            ts += __shfl_xor(ts, 16);
            ts += __shfl_xor(ts, 32);
            const float scale = __expf(m_run - nm);
            s_run = s_run * scale + ts;
            m_run = nm;
            if (lane < 16) sc_lds[w * 16 + r] = scale;
        }
        __syncthreads();
        // ---- rescale accO by per-n scale
        {
            float scj[4];
#pragma unroll
            for (int j = 0; j < 4; ++j) scj[j] = sc_lds[j * 16 + r];
#pragma unroll
            for (int i = 0; i < 4; ++i)
#pragma unroll
                for (int j = 0; j < 4; ++j)
#pragma unroll
                    for (int q = 0; q < 4; ++q) accO[i][j][q] *= scj[j];
        }
        // ---- PV: O[c][n] += V[c][m-chunk] * P[n][m-chunk]
#pragma unroll 1
        for (int vc = 0; vc < 2; ++vc) {
            {   // stage Vs: 256 c-rows x 64 m; thread t owns full row t
                const bf16x8* sv = reinterpret_cast<const bf16x8*>(
                    VB + ((size_t)b * CH + t) * HW + m0 + vc * 64);
                bf16x8* dv = reinterpret_cast<bf16x8*>(Vs + t * VSTRD);
#pragma unroll
                for (int u = 0; u < 8; ++u) dv[u] = sv[u];
            }
            __syncthreads();
            __builtin_amdgcn_s_setprio(1);
#pragma unroll
            for (int kk = 0; kk < 2; ++kk) {
                bf16x8 av[4], bp[4];
#pragma unroll
                for (int i = 0; i < 4; ++i)
                    av[i] = *reinterpret_cast<const bf16x8*>(
                        Vs + (w * 64 + i * 16 + r) * VSTRD + kk * 32 + g * 8);
#pragma unroll
                for (int j = 0; j < 4; ++j)
                    bp[j] = *reinterpret_cast<const bf16x8*>(
                        P_lds + (j * 16 + r) * PSTRD + vc * 64 + kk * 32 + g * 8);
#pragma unroll
                for (int i = 0; i < 4; ++i)
#pragma unroll
                    for (int j = 0; j < 4; ++j)
                        accO[i][j] = __builtin_amdgcn_mfma_f32_16x16x32_bf16(av[i], bp[j], accO[i][j], 0, 0, 0);
            }
            __builtin_amdgcn_s_setprio(0);
            __syncthreads();
        }
    }

    // ---- epilogue: out = gamma * (1/s) * accO + src
    if (lane < 16) sc_lds[w * 16 + r] = 1.f / s_run;
    __syncthreads();
    float IS_l[4];
#pragma unroll
    for (int j = 0; j < 4; ++j) IS_l[j] = sc_lds[j * 16 + r];
    const float gm = gmp[0];
#pragma unroll
    for (int i = 0; i < 4; ++i)
#pragma unroll
        for (int j = 0; j < 4; ++j) {
            const int cb = w * 64 + i * 16 + g * 4;
            const int n  = n0 + j * 16 + r;
            const float sc = gm * IS_l[j];
            float vals[4];
#pragma unroll
            for (int q = 0; q < 4; ++q) {
                const size_t idx = ((size_t)b * CH + cb + q) * HW + n;
                vals[q] = sc * accO[i][j][q] + src[idx];
                A[idx] = vals[q];
            }
            bf16x4 pk;
#pragma unroll
            for (int q = 0; q < 4; ++q) pk[q] = (__bf16)vals[q];
            *reinterpret_cast<bf16x4*>(AT + ((size_t)b * HW + n) * 512 + aoff + cb) = pk;
        }
}

// ---------------------------------------------------------------------------
// wprep: fw1 [64][512*9] fp32 -> WT bf16 [tap][m][512]
__global__ __launch_bounds__(256) void wprep(const float* __restrict__ fw1,
                                             __bf16* __restrict__ WT)
{
    const int i = blockIdx.x * 256 + threadIdx.x;   // 9*64*512 exact
    const int tap = i >> 15;
    const int rem = i & 32767;
    const int m = rem >> 9, c = rem & 511;
    WT[i] = (__bf16)fw1[(size_t)m * 4608 + c * 9 + tap];
}

// ---------------------------------------------------------------------------
// conv1 v2 [proven r4-r7 verbatim]
__global__ __launch_bounds__(256) void conv1_v2(
    const __bf16* __restrict__ AT, const __bf16* __restrict__ WT,
    float* __restrict__ P4)
{
    __shared__ __bf16 A9[9 * 64 * CSTR];
    __shared__ __bf16 HALO[240 * CSTR];
    const int kc = blockIdx.y, b = blockIdx.z, n0 = blockIdx.x * 128;
    const int t = threadIdx.x, lane = t & 63, wid = t >> 6;
    const int r = lane & 15, g = lane >> 4;

    int yj[2], xj[2];
#pragma unroll
    for (int j = 0; j < 2; ++j) {
        const int p = n0 + wid * 32 + j * 16 + r;
        yj[j] = p / IMG; xj[j] = p - yj[j] * IMG;
    }

    f32x4 acc[4][2] = {};

#pragma unroll 1
    for (int st = 0; st < 4; ++st) {
        const int cbase = kc * 128 + st * 32;
        if (t < 240) {
            const int nn = n0 - 56 + t;
            bf16x8 h0 = {}, h1 = {}, h2 = {}, h3 = {};
            if (nn >= 0 && nn < HW) {
                const bf16x8* sp = reinterpret_cast<const bf16x8*>(
                    AT + ((size_t)b * HW + nn) * 512 + cbase);
                h0 = sp[0]; h1 = sp[1]; h2 = sp[2]; h3 = sp[3];
            }
            bf16x8* dp = reinterpret_cast<bf16x8*>(HALO + t * CSTR);
            dp[0] = h0; dp[1] = h1; dp[2] = h2; dp[3] = h3;
        }
        {
            const int m = t >> 2, seg = t & 3;
#pragma unroll
            for (int tap = 0; tap < 9; ++tap)
                *reinterpret_cast<bf16x8*>(A9 + (tap * 64 + m) * CSTR + seg * 8) =
                    *reinterpret_cast<const bf16x8*>(WT + ((size_t)tap * 64 + m) * 512 + cbase + seg * 8);
        }
        __syncthreads();
#pragma unroll 1
        for (int tap = 0; tap < 9; ++tap) {
            const int dy = tap / 3 - 1;
            const int dx = tap - (tap / 3) * 3 - 1;
            bf16x8 bb[2];
#pragma unroll
            for (int j = 0; j < 2; ++j) {
                const bool valid = ((unsigned)(yj[j] + dy) < (unsigned)IMG) &&
                                   ((unsigned)(xj[j] + dx) < (unsigned)IMG);
                const int row = wid * 32 + j * 16 + r + 56 + dy * IMG + dx;
                bf16x8 v = {};
                if (valid) v = *reinterpret_cast<const bf16x8*>(HALO + row * CSTR + g * 8);
                bb[j] = v;
            }
            bf16x8 a[4];
#pragma unroll
            for (int i = 0; i < 4; ++i)
                a[i] = *reinterpret_cast<const bf16x8*>(A9 + (tap * 64 + i * 16 + r) * CSTR + g * 8);
#pragma unroll
            for (int i = 0; i < 4; ++i)
#pragma unroll
                for (int j = 0; j < 2; ++j)
                    acc[i][j] = __builtin_amdgcn_mfma_f32_16x16x32_bf16(a[i], bb[j], acc[i][j], 0, 0, 0);
        }
        __syncthreads();
    }
#pragma unroll
    for (int mi = 0; mi < 4; ++mi)
#pragma unroll
        for (int nj = 0; nj < 2; ++nj) {
            const int m = mi * 16 + g * 4;
            const int n = n0 + wid * 32 + nj * 16 + r;
#pragma unroll
            for (int q = 0; q < 4; ++q)
                P4[(((size_t)kc * BATCH + b) * CG + m + q) * HW + n] = acc[mi][nj][q];
        }
}

// ---------------------------------------------------------------------------
__global__ __launch_bounds__(256) void reduce_hb(
    const float* __restrict__ P4, const float* __restrict__ fb1,
    float* __restrict__ HB)
{
    const int idx = blockIdx.x * 256 + threadIdx.x;
    constexpr size_t STRIDE = (size_t)BATCH * CG * HW;
    const int m = (idx / HW) & 63;
    float s = P4[idx] + P4[idx + STRIDE] + P4[idx + 2 * STRIDE] + P4[idx + 3 * STRIDE];
    HB[idx] = fmaxf(s + fb1[m], 0.f);
}

// ---------------------------------------------------------------------------
__global__ __launch_bounds__(256) void gates_v2(
    const float* __restrict__ hbuf, const float* __restrict__ fw2,
    const float* __restrict__ fb2, float* __restrict__ g0buf)
{
    __shared__ float w2s[1152];
    __shared__ float par[2][4][64];
    const int t = threadIdx.x;
    for (int i = t; i < 1152; i += 256) w2s[i] = fw2[i];
    __syncthreads();
    const int px = t & 63, grp = t >> 6;
    const int idx = blockIdx.x * 64 + px;
    const int b = idx / HW;
    const int n = idx - b * HW;
    const int y = n / IMG, x = n - (n / IMG) * IMG;
    float c0 = 0.f, c1 = 0.f;
    const float* hb = hbuf + ((size_t)b * CG + grp * 16) * HW;
    for (int ci = 0; ci < 16; ++ci) {
        const float* hp = hb + (size_t)ci * HW;
        const float* w0 = &w2s[(grp * 16 + ci) * 9];
        const float* w1 = &w2s[576 + (grp * 16 + ci) * 9];
#pragma unroll
        for (int tap = 0; tap < 9; ++tap) {
            const int dy = tap / 3 - 1, dx = tap % 3 - 1;
            const int yy = y + dy, xx = x + dx;
            if (yy >= 0 && yy < IMG && xx >= 0 && xx < IMG) {
                const float hv = hp[yy * IMG + xx];
                c0 = fmaf(hv, w0[tap], c0);
                c1 = fmaf(hv, w1[tap], c1);
            }
        }
    }
    par[0][grp][px] = c0;
    par[1][grp][px] = c1;
    __syncthreads();
    if (t < 64) {
        const float s0 = par[0][0][t] + par[0][1][t] + par[0][2][t] + par[0][3][t] + fb2[0];
        const float s1 = par[1][0][t] + par[1][1][t] + par[1][2][t] + par[1][3][t] + fb2[1];
        g0buf[blockIdx.x * 64 + t] = 1.f / (1.f + __expf(s1 - s0));
    }
}

// ---------------------------------------------------------------------------
__global__ __launch_bounds__(256) void blend_kernel(
    const float* __restrict__ att1, const float* __restrict__ att2,
    const float* __restrict__ g0buf, float* __restrict__ out)
{
    const int i = blockIdx.x * 256 + threadIdx.x;
    const int r = i / 576;
    const int q = i - r * 576;
    const int b = r >> 8;
    const float4 a1 = reinterpret_cast<const float4*>(att1)[i];
    const float4 a2 = reinterpret_cast<const float4*>(att2)[i];
    const float4 g  = *reinterpret_cast<const float4*>(&g0buf[(size_t)b * HW + q * 4]);
    float4 o;
    o.x = g.x * a1.x + (1.f - g.x) * a2.x;
    o.y = g.y * a1.y + (1.f - g.y) * a2.y;
    o.z = g.z * a1.z + (1.f - g.z) * a2.z;
    o.w = g.w * a1.w + (1.f - g.w) * a2.w;
    reinterpret_cast<float4*>(out)[i] = o;
}

} // namespace

extern "C" void kernel_launch(void* const* d_in, const int* in_sizes, int n_in,
                              void* d_out, int out_size, void* d_ws, size_t ws_size,
                              hipStream_t stream)
{
    const float* x1  = (const float*)d_in[0];
    const float* x2  = (const float*)d_in[1];
    const float* wq1 = (const float*)d_in[2];
    const float* wk1 = (const float*)d_in[3];
    const float* wv1 = (const float*)d_in[4];
    const float* bv1 = (const float*)d_in[5];
    const float* g1  = (const float*)d_in[6];
    const float* wq2 = (const float*)d_in[7];
    const float* wk2 = (const float*)d_in[8];
    const float* wv2 = (const float*)d_in[9];
    const float* bv2 = (const float*)d_in[10];
    const float* g2  = (const float*)d_in[11];
    const float* fw1 = (const float*)d_in[12];
    const float* fb1 = (const float*)d_in[13];
    const float* fw2 = (const float*)d_in[14];
    const float* fb2 = (const float*)d_in[15];
    float* out = (float*)d_out;
    char*  wsb = (char*)d_ws;

    __bf16* QT1 = (__bf16*)(wsb + QT1_OFF);
    __bf16* KT1 = (__bf16*)(wsb + KT1_OFF);
    __bf16* VB1 = (__bf16*)(wsb + VB1_OFF);
    __bf16* QT2 = (__bf16*)(wsb + QT2_OFF);
    __bf16* KT2 = (__bf16*)(wsb + KT2_OFF);
    __bf16* VB2 = (__bf16*)(wsb + VB2_OFF);
    __bf16* AT  = (__bf16*)(wsb + AT_OFF);
    float*  A1  = (float*)(wsb + A1_OFF);
    float*  A2  = (float*)(wsb + A2_OFF);
    float*  HB  = (float*)(wsb + HB_OFF);
    float*  G0  = (float*)(wsb + G0_OFF);
    __bf16* WT  = (__bf16*)(wsb + WT_OFF);
    float*  P4  = (float*)(wsb + QT1_OFF);   // alias: free after attention

    (void)in_sizes; (void)n_in; (void)out_size; (void)ws_size;

    proj3_mfma<<<dim3(18, 2, 24), 256, 0, stream>>>(x1, x2, wq1, wk1, wv1, bv1, QT1, KT1, VB1);
    proj3_mfma<<<dim3(18, 2, 24), 256, 0, stream>>>(x2, x1, wq2, wk2, wv2, bv2, QT2, KT2, VB2);
    wprep<<<dim3(1152), 256, 0, stream>>>(fw1, WT);

    fused_flash<<<dim3(576), 256, 0, stream>>>(
        QT1, KT1, VB1, QT2, KT2, VB2, x1, x2, g1, g2, A1, A2, AT);

    conv1_v2<<<dim3(18, 4, 8), 256, 0, stream>>>(AT, WT, P4);
    reduce_hb<<<dim3(4608), 256, 0, stream>>>(P4, fb1, HB);
    gates_v2<<<dim3(288), 256, 0, stream>>>(HB, fw2, fb2, G0);
    blend_kernel<<<dim3(4608), 256, 0, stream>>>(A1, A2, G0, out);
}

// Round 9
// 396.333 us; speedup vs baseline: 6.9505x; 1.2077x over previous
//
#include <hip/hip_runtime.h>

namespace {

constexpr int BATCH = 8;
constexpr int CH    = 256;   // C
constexpr int HW    = 2304;  // 48*48
constexpr int IMG   = 48;
constexpr int CG    = 64;

typedef __bf16 bf16x8 __attribute__((ext_vector_type(8)));
typedef __bf16 bf16x4 __attribute__((ext_vector_type(4)));
typedef float  f32x4  __attribute__((ext_vector_type(4)));

constexpr int ROWB = 40;    // proj LDS row stride
constexpr int KSTRD = 136;  // flash K-tile stride (128 data + 8 pad, 272B = 17 granules)
constexpr int PSTRD = 136;  // flash P stride (128 data + 8 pad, odd-granule => uniform banks)
constexpr int CSTR = 40;    // conv LDS stride

// ---- ws layout (bytes) ----
constexpr size_t BF_SLAB = (size_t)BATCH * HW * CH * 2;      // 9,437,184
constexpr size_t QT1_OFF = 0;
constexpr size_t KT1_OFF = 1 * BF_SLAB;
constexpr size_t VB1_OFF = 2 * BF_SLAB;
constexpr size_t QT2_OFF = 3 * BF_SLAB;
constexpr size_t KT2_OFF = 4 * BF_SLAB;
constexpr size_t VB2_OFF = 5 * BF_SLAB;
constexpr size_t AT_OFF  = 6 * BF_SLAB;                      // bf16 [B][HW][512]
constexpr size_t A1_OFF  = AT_OFF + (size_t)BATCH * HW * 512 * 2;
constexpr size_t A2_OFF  = A1_OFF + (size_t)BATCH * CH * HW * 4;
constexpr size_t HB_OFF  = A2_OFF + (size_t)BATCH * CH * HW * 4;
constexpr size_t G0_OFF  = HB_OFF + (size_t)BATCH * CG * HW * 4;
constexpr size_t WT_OFF  = G0_OFF + (size_t)BATCH * HW * 4;
// end ~= 112 MB; P4 (conv partials) aliases QT1/KT1 slabs.

// stage 16 fp32 elems/thread (convert to bf16) into [128][ROWB] LDS (256-thr)
__device__ __forceinline__ void stage_f32(const float* __restrict__ src, size_t srcStride,
                                          __bf16* dst, int t) {
    const int r = t & 127, s = t >> 7;
    const float4* sp = reinterpret_cast<const float4*>(src + (size_t)r * srcStride + s * 16);
    float4 f0 = sp[0], f1 = sp[1], f2 = sp[2], f3 = sp[3];
    bf16x8 v0, v1;
    v0[0]=(__bf16)f0.x; v0[1]=(__bf16)f0.y; v0[2]=(__bf16)f0.z; v0[3]=(__bf16)f0.w;
    v0[4]=(__bf16)f1.x; v0[5]=(__bf16)f1.y; v0[6]=(__bf16)f1.z; v0[7]=(__bf16)f1.w;
    v1[0]=(__bf16)f2.x; v1[1]=(__bf16)f2.y; v1[2]=(__bf16)f2.z; v1[3]=(__bf16)f2.w;
    v1[4]=(__bf16)f3.x; v1[5]=(__bf16)f3.y; v1[6]=(__bf16)f3.z; v1[7]=(__bf16)f3.w;
    bf16x8* dp = reinterpret_cast<bf16x8*>(dst + r * ROWB + s * 16);
    dp[0] = v0;
    dp[1] = v1;
}

// 4-wave 128x128 MFMA step (proj) [proven r3]
__device__ __forceinline__ void frag_step(const __bf16* As, const __bf16* Bs,
                                          f32x4 (&acc)[4][4], int lane, int wm, int wn) {
    const int r = lane & 15, g = lane >> 4;
    bf16x8 a[4], b[4];
#pragma unroll
    for (int i = 0; i < 4; ++i) {
        a[i] = *reinterpret_cast<const bf16x8*>(As + (wm * 64 + i * 16 + r) * ROWB + g * 8);
        b[i] = *reinterpret_cast<const bf16x8*>(Bs + (wn * 64 + i * 16 + r) * ROWB + g * 8);
    }
#pragma unroll
    for (int i = 0; i < 4; ++i)
#pragma unroll
        for (int j = 0; j < 4; ++j)
            acc[i][j] = __builtin_amdgcn_mfma_f32_16x16x32_bf16(a[i], b[j], acc[i][j], 0, 0, 0);
}

// ---------------------------------------------------------------------------
// proj3: Q/K/V. Q,K TRANSPOSED bf16 [B][HW][256]; V [B][256][HW]. [proven r3-r8]
__global__ __launch_bounds__(256) void proj3_mfma(
    const float* __restrict__ Xsrc, const float* __restrict__ Xg,
    const float* __restrict__ wq, const float* __restrict__ wk,
    const float* __restrict__ wv, const float* __restrict__ bv,
    __bf16* __restrict__ QT, __bf16* __restrict__ KT, __bf16* __restrict__ VB)
{
    __shared__ __bf16 As[128 * ROWB];
    __shared__ __bf16 Bs[128 * ROWB];
    const int p = blockIdx.z >> 3;      // 0=Q 1=K 2=V
    const int b = blockIdx.z & 7;
    const float* W = (p == 0) ? wq : (p == 1) ? wk : wv;
    const float* X = (p == 0) ? Xsrc : Xg;
    const float* Xb = X + (size_t)b * CH * HW;

    const int t = threadIdx.x;
    const int lane = t & 63, wid = t >> 6;
    const int wm = wid >> 1, wn = wid & 1;
    const int m0 = blockIdx.y * 128, n0 = blockIdx.x * 128;

    f32x4 acc[4][4] = {};
    const int nB = t & 127, halfB = t >> 7;

    for (int k0 = 0; k0 < CH; k0 += 32) {
        stage_f32(W + (size_t)m0 * CH + k0, CH, As, t);
        float v[16];
#pragma unroll
        for (int kk = 0; kk < 16; ++kk)
            v[kk] = Xb[(size_t)(k0 + halfB * 16 + kk) * HW + n0 + nB];
        bf16x8 p0, p1;
#pragma unroll
        for (int kk = 0; kk < 8; ++kk) { p0[kk] = (__bf16)v[kk]; p1[kk] = (__bf16)v[kk + 8]; }
        bf16x8* dp = reinterpret_cast<bf16x8*>(Bs + nB * ROWB + halfB * 16);
        dp[0] = p0; dp[1] = p1;
        __syncthreads();
        frag_step(As, Bs, acc, lane, wm, wn);
        __syncthreads();
    }

    const int g = lane >> 4, r = lane & 15;
    if (p < 2) {
        __bf16* T = (p == 0) ? QT : KT;
#pragma unroll
        for (int mi = 0; mi < 4; ++mi)
#pragma unroll
            for (int nj = 0; nj < 4; ++nj) {
                const int mb = m0 + wm * 64 + mi * 16 + g * 4;
                const int n  = n0 + wn * 64 + nj * 16 + r;
                bf16x4 pk;
#pragma unroll
                for (int q = 0; q < 4; ++q) pk[q] = (__bf16)acc[mi][nj][q];
                *reinterpret_cast<bf16x4*>(T + ((size_t)b * HW + n) * CH + mb) = pk;
            }
    } else {
#pragma unroll
        for (int mi = 0; mi < 4; ++mi)
#pragma unroll
            for (int nj = 0; nj < 4; ++nj) {
                const int mb = m0 + wm * 64 + mi * 16 + g * 4;
                const int n  = n0 + wn * 64 + nj * 16 + r;
#pragma unroll
                for (int q = 0; q < 4; ++q)
                    VB[((size_t)b * CH + mb + q) * HW + n] = (__bf16)(acc[mi][nj][q] + bv[mb + q]);
            }
    }
}

// ---------------------------------------------------------------------------
// fused_flash v3: single-sweep flash attention, swapped-operand S, V direct
// from global (no V LDS), K register-prefetch pipeline, 4 barriers per m-tile.
// 256 thr (4 waves), QBLK=64. grid 576 = 36 n-tiles x 16 z, XCD-swizzled.
__global__ __launch_bounds__(256, 2) void fused_flash(
    const __bf16* __restrict__ QT1, const __bf16* __restrict__ KT1, const __bf16* __restrict__ VB1,
    const __bf16* __restrict__ QT2, const __bf16* __restrict__ KT2, const __bf16* __restrict__ VB2,
    const float* __restrict__ x1, const float* __restrict__ x2,
    const float* __restrict__ g1, const float* __restrict__ g2,
    float* __restrict__ A1, float* __restrict__ A2, __bf16* __restrict__ AT)
{
    __shared__ __bf16 Ks[128 * KSTRD];     // 34.8 KB
    __shared__ __bf16 P_lds[64 * PSTRD];   // 17.4 KB, [q-row 64][m 128]
    __shared__ float  sc_lds[64];

    // XCD swizzle: 576 = 8 * 72; contiguous 72-block chunk (2 z) per XCD
    const int bid  = blockIdx.x;
    const int work = (bid & 7) * 72 + (bid >> 3);
    const int z = work / 36, ntile = work - z * 36;

    const int att = z >> 3, b = z & 7;
    const __bf16* QT = att ? QT2 : QT1;
    const __bf16* KT = att ? KT2 : KT1;
    const __bf16* VB = att ? VB2 : VB1;
    const float* src = att ? x2 : x1;
    const float* gmp = att ? g2 : g1;
    float* A         = att ? A2 : A1;
    const int aoff   = att ? CH : 0;

    const int t = threadIdx.x, lane = t & 63, w = t >> 6;
    const int r = lane & 15, g = lane >> 4;
    const int n0 = ntile * 64;
    const __bf16* KTb = KT + (size_t)b * HW * CH;
    const __bf16* VBb = VB + (size_t)b * CH * HW;

    // Q row in registers: q-row n0 + w*16 + r, full K=256
    bf16x8 qf[8];
    {
        const __bf16* qrow = QT + ((size_t)b * HW + n0 + w * 16 + r) * CH;
#pragma unroll
        for (int kc = 0; kc < 8; ++kc)
            qf[kc] = *reinterpret_cast<const bf16x8*>(qrow + kc * 32 + g * 8);
    }

    // K staging geometry: thread owns row t>>1, 64-col half (t&1)
    const int kr = t >> 1, kcol = (t & 1) * 64;
    bf16x8 kbuf[8];
    {   // preload m0=0, half0
        const bf16x8* sp = reinterpret_cast<const bf16x8*>(KTb + (size_t)kr * CH + kcol);
#pragma unroll
        for (int u = 0; u < 8; ++u) kbuf[u] = sp[u];
    }

    float m_run = -3.0e38f;
    float s_run = 0.f;
    f32x4 accO[4][4] = {};

    for (int m0 = 0; m0 < HW; m0 += 128) {
        f32x4 accS[8] = {};
        // ================= phase A: K half0 =================
        {
            bf16x8* dp = reinterpret_cast<bf16x8*>(Ks + kr * KSTRD + kcol);
#pragma unroll
            for (int u = 0; u < 8; ++u) dp[u] = kbuf[u];
        }
        __syncthreads();                              // b1: half0 visible
        {   // prefetch K half1 (hides under MFMA half0)
            const bf16x8* sp = reinterpret_cast<const bf16x8*>(
                KTb + (size_t)(m0 + kr) * CH + 128 + kcol);
#pragma unroll
            for (int u = 0; u < 8; ++u) kbuf[u] = sp[u];
        }
        __builtin_amdgcn_s_setprio(1);
#pragma unroll
        for (int kk = 0; kk < 4; ++kk) {
            const bf16x8 qv = qf[kk];
#pragma unroll
            for (int j = 0; j < 8; ++j) {
                const bf16x8 kf = *reinterpret_cast<const bf16x8*>(
                    Ks + (j * 16 + r) * KSTRD + kk * 32 + g * 8);
                accS[j] = __builtin_amdgcn_mfma_f32_16x16x32_bf16(kf, qv, accS[j], 0, 0, 0);
            }
        }
        __builtin_amdgcn_s_setprio(0);
        __syncthreads();                              // b2: half0 reads done
        // ================= phase B: K half1 =================
        {
            bf16x8* dp = reinterpret_cast<bf16x8*>(Ks + kr * KSTRD + kcol);
#pragma unroll
            for (int u = 0; u < 8; ++u) dp[u] = kbuf[u];
        }
        __syncthreads();                              // b3: half1 visible
        {   // prefetch next m-tile's K half0
            const int m0n = (m0 + 128 < HW) ? (m0 + 128) : 0;
            const bf16x8* sp = reinterpret_cast<const bf16x8*>(
                KTb + (size_t)(m0n + kr) * CH + kcol);
#pragma unroll
            for (int u = 0; u < 8; ++u) kbuf[u] = sp[u];
        }
        // prefetch V fragments for vc0 (hides under MFMA half1 + softmax)
        bf16x8 av0[8];
#pragma unroll
        for (int kk = 0; kk < 2; ++kk)
#pragma unroll
            for (int i = 0; i < 4; ++i)
                av0[kk * 4 + i] = *reinterpret_cast<const bf16x8*>(
                    VBb + (size_t)(w * 64 + i * 16 + r) * HW + m0 + kk * 32 + g * 8);
        __builtin_amdgcn_s_setprio(1);
#pragma unroll
        for (int kk = 0; kk < 4; ++kk) {
            const bf16x8 qv = qf[4 + kk];
#pragma unroll
            for (int j = 0; j < 8; ++j) {
                const bf16x8 kf = *reinterpret_cast<const bf16x8*>(
                    Ks + (j * 16 + r) * KSTRD + kk * 32 + g * 8);
                accS[j] = __builtin_amdgcn_mfma_f32_16x16x32_bf16(kf, qv, accS[j], 0, 0, 0);
            }
        }
        __builtin_amdgcn_s_setprio(0);
        // ---- in-lane online softmax (tree reductions) ----
        {
            float mj[8];
#pragma unroll
            for (int j = 0; j < 8; ++j)
                mj[j] = fmaxf(fmaxf(accS[j][0], accS[j][1]), fmaxf(accS[j][2], accS[j][3]));
            float m03 = fmaxf(fmaxf(mj[0], mj[1]), fmaxf(mj[2], mj[3]));
            float m47 = fmaxf(fmaxf(mj[4], mj[5]), fmaxf(mj[6], mj[7]));
            float tmax = fmaxf(m03, m47);
            tmax = fmaxf(tmax, __shfl_xor(tmax, 16));
            tmax = fmaxf(tmax, __shfl_xor(tmax, 32));
            const float nm = fmaxf(m_run, tmax);
            float tsj[8];
#pragma unroll
            for (int j = 0; j < 8; ++j) {
                const float pe0 = __expf(accS[j][0] - nm);
                const float pe1 = __expf(accS[j][1] - nm);
                const float pe2 = __expf(accS[j][2] - nm);
                const float pe3 = __expf(accS[j][3] - nm);
                tsj[j] = (pe0 + pe1) + (pe2 + pe3);
                bf16x4 pk;
                pk[0] = (__bf16)pe0; pk[1] = (__bf16)pe1;
                pk[2] = (__bf16)pe2; pk[3] = (__bf16)pe3;
                *reinterpret_cast<bf16x4*>(
                    P_lds + (w * 16 + r) * PSTRD + j * 16 + g * 4) = pk;
            }
            float ts = ((tsj[0] + tsj[1]) + (tsj[2] + tsj[3])) +
                       ((tsj[4] + tsj[5]) + (tsj[6] + tsj[7]));
            ts += __shfl_xor(ts, 16);
            ts += __shfl_xor(ts, 32);
            const float scale = __expf(m_run - nm);
            s_run = s_run * scale + ts;
            m_run = nm;
            if (lane < 16) sc_lds[w * 16 + r] = scale;
        }
        __syncthreads();                              // b4: P + sc visible
        // ---- rescale accO by per-n scale
        {
            float scj[4];
#pragma unroll
            for (int j = 0; j < 4; ++j) scj[j] = sc_lds[j * 16 + r];
#pragma unroll
            for (int i = 0; i < 4; ++i)
#pragma unroll
                for (int j = 0; j < 4; ++j)
#pragma unroll
                    for (int q = 0; q < 4; ++q) accO[i][j][q] *= scj[j];
        }
        // ---- PV: av direct from global, bp from P_lds. vc1 loads prefetched.
        bf16x8 av1[8];
#pragma unroll
        for (int kk = 0; kk < 2; ++kk)
#pragma unroll
            for (int i = 0; i < 4; ++i)
                av1[kk * 4 + i] = *reinterpret_cast<const bf16x8*>(
                    VBb + (size_t)(w * 64 + i * 16 + r) * HW + m0 + 64 + kk * 32 + g * 8);
        __builtin_amdgcn_s_setprio(1);
#pragma unroll
        for (int kk = 0; kk < 2; ++kk) {
            bf16x8 bp[4];
#pragma unroll
            for (int j = 0; j < 4; ++j)
                bp[j] = *reinterpret_cast<const bf16x8*>(
                    P_lds + (j * 16 + r) * PSTRD + kk * 32 + g * 8);
#pragma unroll
            for (int i = 0; i < 4; ++i)
#pragma unroll
                for (int j = 0; j < 4; ++j)
                    accO[i][j] = __builtin_amdgcn_mfma_f32_16x16x32_bf16(
                        av0[kk * 4 + i], bp[j], accO[i][j], 0, 0, 0);
        }
#pragma unroll
        for (int kk = 0; kk < 2; ++kk) {
            bf16x8 bp[4];
#pragma unroll
            for (int j = 0; j < 4; ++j)
                bp[j] = *reinterpret_cast<const bf16x8*>(
                    P_lds + (j * 16 + r) * PSTRD + 64 + kk * 32 + g * 8);
#pragma unroll
            for (int i = 0; i < 4; ++i)
#pragma unroll
                for (int j = 0; j < 4; ++j)
                    accO[i][j] = __builtin_amdgcn_mfma_f32_16x16x32_bf16(
                        av1[kk * 4 + i], bp[j], accO[i][j], 0, 0, 0);
        }
        __builtin_amdgcn_s_setprio(0);
        // no barrier here: next tile's b1..b3 guard P/Ks WAR hazards
    }

    // ---- epilogue: out = gamma * (1/s) * accO + src
    if (lane < 16) sc_lds[w * 16 + r] = 1.f / s_run;
    __syncthreads();
    float IS_l[4];
#pragma unroll
    for (int j = 0; j < 4; ++j) IS_l[j] = sc_lds[j * 16 + r];
    const float gm = gmp[0];
#pragma unroll
    for (int i = 0; i < 4; ++i)
#pragma unroll
        for (int j = 0; j < 4; ++j) {
            const int cb = w * 64 + i * 16 + g * 4;
            const int n  = n0 + j * 16 + r;
            const float sc = gm * IS_l[j];
            float vals[4];
#pragma unroll
            for (int q = 0; q < 4; ++q) {
                const size_t idx = ((size_t)b * CH + cb + q) * HW + n;
                vals[q] = sc * accO[i][j][q] + src[idx];
                A[idx] = vals[q];
            }
            bf16x4 pk;
#pragma unroll
            for (int q = 0; q < 4; ++q) pk[q] = (__bf16)vals[q];
            *reinterpret_cast<bf16x4*>(AT + ((size_t)b * HW + n) * 512 + aoff + cb) = pk;
        }
}

// ---------------------------------------------------------------------------
// wprep: fw1 [64][512*9] fp32 -> WT bf16 [tap][m][512]
__global__ __launch_bounds__(256) void wprep(const float* __restrict__ fw1,
                                             __bf16* __restrict__ WT)
{
    const int i = blockIdx.x * 256 + threadIdx.x;   // 9*64*512 exact
    const int tap = i >> 15;
    const int rem = i & 32767;
    const int m = rem >> 9, c = rem & 511;
    WT[i] = (__bf16)fw1[(size_t)m * 4608 + c * 9 + tap];
}

// ---------------------------------------------------------------------------
// conv1 v2 [proven r4-r8 verbatim]
__global__ __launch_bounds__(256) void conv1_v2(
    const __bf16* __restrict__ AT, const __bf16* __restrict__ WT,
    float* __restrict__ P4)
{
    __shared__ __bf16 A9[9 * 64 * CSTR];
    __shared__ __bf16 HALO[240 * CSTR];
    const int kc = blockIdx.y, b = blockIdx.z, n0 = blockIdx.x * 128;
    const int t = threadIdx.x, lane = t & 63, wid = t >> 6;
    const int r = lane & 15, g = lane >> 4;

    int yj[2], xj[2];
#pragma unroll
    for (int j = 0; j < 2; ++j) {
        const int p = n0 + wid * 32 + j * 16 + r;
        yj[j] = p / IMG; xj[j] = p - yj[j] * IMG;
    }

    f32x4 acc[4][2] = {};

#pragma unroll 1
    for (int st = 0; st < 4; ++st) {
        const int cbase = kc * 128 + st * 32;
        if (t < 240) {
            const int nn = n0 - 56 + t;
            bf16x8 h0 = {}, h1 = {}, h2 = {}, h3 = {};
            if (nn >= 0 && nn < HW) {
                const bf16x8* sp = reinterpret_cast<const bf16x8*>(
                    AT + ((size_t)b * HW + nn) * 512 + cbase);
                h0 = sp[0]; h1 = sp[1]; h2 = sp[2]; h3 = sp[3];
            }
            bf16x8* dp = reinterpret_cast<bf16x8*>(HALO + t * CSTR);
            dp[0] = h0; dp[1] = h1; dp[2] = h2; dp[3] = h3;
        }
        {
            const int m = t >> 2, seg = t & 3;
#pragma unroll
            for (int tap = 0; tap < 9; ++tap)
                *reinterpret_cast<bf16x8*>(A9 + (tap * 64 + m) * CSTR + seg * 8) =
                    *reinterpret_cast<const bf16x8*>(WT + ((size_t)tap * 64 + m) * 512 + cbase + seg * 8);
        }
        __syncthreads();
#pragma unroll 1
        for (int tap = 0; tap < 9; ++tap) {
            const int dy = tap / 3 - 1;
            const int dx = tap - (tap / 3) * 3 - 1;
            bf16x8 bb[2];
#pragma unroll
            for (int j = 0; j < 2; ++j) {
                const bool valid = ((unsigned)(yj[j] + dy) < (unsigned)IMG) &&
                                   ((unsigned)(xj[j] + dx) < (unsigned)IMG);
                const int row = wid * 32 + j * 16 + r + 56 + dy * IMG + dx;
                bf16x8 v = {};
                if (valid) v = *reinterpret_cast<const bf16x8*>(HALO + row * CSTR + g * 8);
                bb[j] = v;
            }
            bf16x8 a[4];
#pragma unroll
            for (int i = 0; i < 4; ++i)
                a[i] = *reinterpret_cast<const bf16x8*>(A9 + (tap * 64 + i * 16 + r) * CSTR + g * 8);
#pragma unroll
            for (int i = 0; i < 4; ++i)
#pragma unroll
                for (int j = 0; j < 2; ++j)
                    acc[i][j] = __builtin_amdgcn_mfma_f32_16x16x32_bf16(a[i], bb[j], acc[i][j], 0, 0, 0);
        }
        __syncthreads();
    }
#pragma unroll
    for (int mi = 0; mi < 4; ++mi)
#pragma unroll
        for (int nj = 0; nj < 2; ++nj) {
            const int m = mi * 16 + g * 4;
            const int n = n0 + wid * 32 + nj * 16 + r;
#pragma unroll
            for (int q = 0; q < 4; ++q)
                P4[(((size_t)kc * BATCH + b) * CG + m + q) * HW + n] = acc[mi][nj][q];
        }
}

// ---------------------------------------------------------------------------
__global__ __launch_bounds__(256) void reduce_hb(
    const float* __restrict__ P4, const float* __restrict__ fb1,
    float* __restrict__ HB)
{
    const int idx = blockIdx.x * 256 + threadIdx.x;
    constexpr size_t STRIDE = (size_t)BATCH * CG * HW;
    const int m = (idx / HW) & 63;
    float s = P4[idx] + P4[idx + STRIDE] + P4[idx + 2 * STRIDE] + P4[idx + 3 * STRIDE];
    HB[idx] = fmaxf(s + fb1[m], 0.f);
}

// ---------------------------------------------------------------------------
__global__ __launch_bounds__(256) void gates_v2(
    const float* __restrict__ hbuf, const float* __restrict__ fw2,
    const float* __restrict__ fb2, float* __restrict__ g0buf)
{
    __shared__ float w2s[1152];
    __shared__ float par[2][4][64];
    const int t = threadIdx.x;
    for (int i = t; i < 1152; i += 256) w2s[i] = fw2[i];
    __syncthreads();
    const int px = t & 63, grp = t >> 6;
    const int idx = blockIdx.x * 64 + px;
    const int b = idx / HW;
    const int n = idx - b * HW;
    const int y = n / IMG, x = n - (n / IMG) * IMG;
    float c0 = 0.f, c1 = 0.f;
    const float* hb = hbuf + ((size_t)b * CG + grp * 16) * HW;
    for (int ci = 0; ci < 16; ++ci) {
        const float* hp = hb + (size_t)ci * HW;
        const float* w0 = &w2s[(grp * 16 + ci) * 9];
        const float* w1 = &w2s[576 + (grp * 16 + ci) * 9];
#pragma unroll
        for (int tap = 0; tap < 9; ++tap) {
            const int dy = tap / 3 - 1, dx = tap % 3 - 1;
            const int yy = y + dy, xx = x + dx;
            if (yy >= 0 && yy < IMG && xx >= 0 && xx < IMG) {
                const float hv = hp[yy * IMG + xx];
                c0 = fmaf(hv, w0[tap], c0);
                c1 = fmaf(hv, w1[tap], c1);
            }
        }
    }
    par[0][grp][px] = c0;
    par[1][grp][px] = c1;
    __syncthreads();
    if (t < 64) {
        const float s0 = par[0][0][t] + par[0][1][t] + par[0][2][t] + par[0][3][t] + fb2[0];
        const float s1 = par[1][0][t] + par[1][1][t] + par[1][2][t] + par[1][3][t] + fb2[1];
        g0buf[blockIdx.x * 64 + t] = 1.f / (1.f + __expf(s1 - s0));
    }
}

// ---------------------------------------------------------------------------
__global__ __launch_bounds__(256) void blend_kernel(
    const float* __restrict__ att1, const float* __restrict__ att2,
    const float* __restrict__ g0buf, float* __restrict__ out)
{
    const int i = blockIdx.x * 256 + threadIdx.x;
    const int r = i / 576;
    const int q = i - r * 576;
    const int b = r >> 8;
    const float4 a1 = reinterpret_cast<const float4*>(att1)[i];
    const float4 a2 = reinterpret_cast<const float4*>(att2)[i];
    const float4 g  = *reinterpret_cast<const float4*>(&g0buf[(size_t)b * HW + q * 4]);
    float4 o;
    o.x = g.x * a1.x + (1.f - g.x) * a2.x;
    o.y = g.y * a1.y + (1.f - g.y) * a2.y;
    o.z = g.z * a1.z + (1.f - g.z) * a2.z;
    o.w = g.w * a1.w + (1.f - g.w) * a2.w;
    reinterpret_cast<float4*>(out)[i] = o;
}

} // namespace

extern "C" void kernel_launch(void* const* d_in, const int* in_sizes, int n_in,
                              void* d_out, int out_size, void* d_ws, size_t ws_size,
                              hipStream_t stream)
{
    const float* x1  = (const float*)d_in[0];
    const float* x2  = (const float*)d_in[1];
    const float* wq1 = (const float*)d_in[2];
    const float* wk1 = (const float*)d_in[3];
    const float* wv1 = (const float*)d_in[4];
    const float* bv1 = (const float*)d_in[5];
    const float* g1  = (const float*)d_in[6];
    const float* wq2 = (const float*)d_in[7];
    const float* wk2 = (const float*)d_in[8];
    const float* wv2 = (const float*)d_in[9];
    const float* bv2 = (const float*)d_in[10];
    const float* g2  = (const float*)d_in[11];
    const float* fw1 = (const float*)d_in[12];
    const float* fb1 = (const float*)d_in[13];
    const float* fw2 = (const float*)d_in[14];
    const float* fb2 = (const float*)d_in[15];
    float* out = (float*)d_out;
    char*  wsb = (char*)d_ws;

    __bf16* QT1 = (__bf16*)(wsb + QT1_OFF);
    __bf16* KT1 = (__bf16*)(wsb + KT1_OFF);
    __bf16* VB1 = (__bf16*)(wsb + VB1_OFF);
    __bf16* QT2 = (__bf16*)(wsb + QT2_OFF);
    __bf16* KT2 = (__bf16*)(wsb + KT2_OFF);
    __bf16* VB2 = (__bf16*)(wsb + VB2_OFF);
    __bf16* AT  = (__bf16*)(wsb + AT_OFF);
    float*  A1  = (float*)(wsb + A1_OFF);
    float*  A2  = (float*)(wsb + A2_OFF);
    float*  HB  = (float*)(wsb + HB_OFF);
    float*  G0  = (float*)(wsb + G0_OFF);
    __bf16* WT  = (__bf16*)(wsb + WT_OFF);
    float*  P4  = (float*)(wsb + QT1_OFF);   // alias: free after attention

    (void)in_sizes; (void)n_in; (void)out_size; (void)ws_size;

    proj3_mfma<<<dim3(18, 2, 24), 256, 0, stream>>>(x1, x2, wq1, wk1, wv1, bv1, QT1, KT1, VB1);
    proj3_mfma<<<dim3(18, 2, 24), 256, 0, stream>>>(x2, x1, wq2, wk2, wv2, bv2, QT2, KT2, VB2);
    wprep<<<dim3(1152), 256, 0, stream>>>(fw1, WT);

    fused_flash<<<dim3(576), 256, 0, stream>>>(
        QT1, KT1, VB1, QT2, KT2, VB2, x1, x2, g1, g2, A1, A2, AT);

    conv1_v2<<<dim3(18, 4, 8), 256, 0, stream>>>(AT, WT, P4);
    reduce_hb<<<dim3(4608), 256, 0, stream>>>(P4, fb1, HB);
    gates_v2<<<dim3(288), 256, 0, stream>>>(HB, fw2, fb2, G0);
    blend_kernel<<<dim3(4608), 256, 0, stream>>>(A1, A2, G0, out);
}